// Round 2
// baseline (1207.967 us; speedup 1.0000x reference)
//
#include <hip/hip_runtime.h>
#include <hip/hip_bf16.h>

// HeteroGCN: 3x SAGEConv(mean).
// Round 1: replaced per-edge atomic scatter (250 MB HBM write-through per etype)
// with device-built CSR + per-node gather aggregation (no atomics), then
// out += agg @ Wn via the fp32 tiled matmul with an accumulate flag.

#define D 128
#define NG 100000
#define NT 100000

constexpr int ROWS_PER_BLOCK = 32;

// out[row][c] = x[row][:] @ (W1 (+W2)) (+ b1 (+ b2)) ; accumulate ? out += : out =
__global__ __launch_bounds__(256) void xw_kernel(
    const float* __restrict__ x, int n_rows,
    const float* __restrict__ W1, const float* __restrict__ W2,
    const float* __restrict__ b1, const float* __restrict__ b2,
    float* __restrict__ out, int accumulate)
{
    __shared__ float Wl[D][D];                 // 64 KiB
    __shared__ float Xl[ROWS_PER_BLOCK][D];    // 16 KiB
    const int t = threadIdx.x;

    {
        const float4* w1 = (const float4*)W1;
        const float4* w2 = (const float4*)W2;
        float4* wl = (float4*)&Wl[0][0];
        for (int i = t; i < D * D / 4; i += 256) {
            float4 v = w1[i];
            if (w2) { float4 u = w2[i]; v.x += u.x; v.y += u.y; v.z += u.z; v.w += u.w; }
            wl[i] = v;
        }
    }
    const int row0 = blockIdx.x * ROWS_PER_BLOCK;
    const int nrow = min(ROWS_PER_BLOCK, n_rows - row0);
    {
        const float4* xg = (const float4*)(x + (size_t)row0 * D);
        float4* xl = (float4*)&Xl[0][0];
        const int nv = nrow * (D / 4);
        for (int i = t; i < nv; i += 256) xl[i] = xg[i];
    }
    __syncthreads();

    const int cg = t & 31;
    const int rg = t >> 5;
    const int c0 = cg * 4;
    constexpr int R = 4;
    const int rbase = rg * R;

    float4 bv = make_float4(0.f, 0.f, 0.f, 0.f);
    if (b1) { float4 u = *(const float4*)(b1 + c0); bv.x += u.x; bv.y += u.y; bv.z += u.z; bv.w += u.w; }
    if (b2) { float4 u = *(const float4*)(b2 + c0); bv.x += u.x; bv.y += u.y; bv.z += u.z; bv.w += u.w; }

    float acc[R][4];
#pragma unroll
    for (int i = 0; i < R; ++i) {
        acc[i][0] = bv.x; acc[i][1] = bv.y; acc[i][2] = bv.z; acc[i][3] = bv.w;
    }

    for (int k = 0; k < D; k += 4) {
        float4 w0 = *(const float4*)&Wl[k + 0][c0];
        float4 w1 = *(const float4*)&Wl[k + 1][c0];
        float4 w2 = *(const float4*)&Wl[k + 2][c0];
        float4 w3 = *(const float4*)&Wl[k + 3][c0];
#pragma unroll
        for (int i = 0; i < R; ++i) {
            float4 xv = *(const float4*)&Xl[rbase + i][k];
            acc[i][0] += xv.x * w0.x + xv.y * w1.x + xv.z * w2.x + xv.w * w3.x;
            acc[i][1] += xv.x * w0.y + xv.y * w1.y + xv.z * w2.y + xv.w * w3.y;
            acc[i][2] += xv.x * w0.z + xv.y * w1.z + xv.z * w2.z + xv.w * w3.z;
            acc[i][3] += xv.x * w0.w + xv.y * w1.w + xv.z * w2.w + xv.w * w3.w;
        }
    }

#pragma unroll
    for (int i = 0; i < R; ++i) {
        const int r = rbase + i;
        if (r < nrow) {
            float4 v = make_float4(acc[i][0], acc[i][1], acc[i][2], acc[i][3]);
            float* p = out + (size_t)(row0 + r) * D + c0;
            if (accumulate) {
                float4 o = *(const float4*)p;
                v.x += o.x; v.y += o.y; v.z += o.z; v.w += o.w;
            }
            *(float4*)p = v;
        }
    }
}

__global__ __launch_bounds__(256) void deg_kernel(
    const int* __restrict__ dst, int* __restrict__ deg, int nE)
{
    int i = blockIdx.x * blockDim.x + threadIdx.x;
    if (i < nE) atomicAdd(&deg[dst[i]], 1);
}

// exclusive scan of deg[0..n) into off[0..n], single block of 1024 threads
__global__ __launch_bounds__(1024) void scan_kernel(
    const int* __restrict__ deg, int* __restrict__ off, int n)
{
    __shared__ int lds[1024];
    const int t = threadIdx.x;
    const int chunk = (n + 1023) / 1024;
    const int s0 = t * chunk;
    const int s1 = min(n, s0 + chunk);
    int sum = 0;
    for (int i = s0; i < s1; ++i) sum += deg[i];
    lds[t] = sum;
    __syncthreads();
    for (int sh = 1; sh < 1024; sh <<= 1) {
        int v = (t >= sh) ? lds[t - sh] : 0;
        __syncthreads();
        lds[t] += v;
        __syncthreads();
    }
    int run = (t == 0) ? 0 : lds[t - 1];
    for (int i = s0; i < s1; ++i) { off[i] = run; run += deg[i]; }
    if (t == 1023) off[n] = lds[1023];
}

__global__ __launch_bounds__(256) void fill_kernel(
    const int* __restrict__ src, const int* __restrict__ dst,
    int* __restrict__ cur, int* __restrict__ sorted, int nE)
{
    int e = blockIdx.x * blockDim.x + threadIdx.x;
    if (e < nE) {
        int p = atomicAdd(&cur[dst[e]], 1);
        sorted[p] = src[e];
    }
}

// one wave per dst node: agg[node] = mean over CSR neighbors of x[src]
__global__ __launch_bounds__(256) void agg_kernel(
    const float* __restrict__ x, const int* __restrict__ off,
    const int* __restrict__ sorted, float* __restrict__ agg, int n_dst)
{
    const int node = blockIdx.x * 4 + (threadIdx.x >> 6);
    if (node >= n_dst) return;
    const int lane = threadIdx.x & 63;
    const int s0 = off[node];
    const int s1 = off[node + 1];
    float2 acc = make_float2(0.f, 0.f);
    for (int e = s0; e < s1; ++e) {
        const int s = sorted[e];
        float2 v = *(const float2*)(x + (size_t)s * D + lane * 2);
        acc.x += v.x; acc.y += v.y;
    }
    const float inv = 1.0f / (float)max(s1 - s0, 1);
    *(float2*)(agg + (size_t)node * D + lane * 2) = make_float2(acc.x * inv, acc.y * inv);
}

extern "C" void kernel_launch(void* const* d_in, const int* in_sizes, int n_in,
                              void* d_out, int out_size, void* d_ws, size_t ws_size,
                              hipStream_t stream)
{
    const float* x_gene  = (const float*)d_in[0];
    const float* x_trait = (const float*)d_in[1];
    const int* src_gg = (const int*)d_in[2];
    const int* dst_gg = (const int*)d_in[3];
    const int* src_gt = (const int*)d_in[4];
    const int* dst_gt = (const int*)d_in[5];
    const int* src_tg = (const int*)d_in[6];
    const int* dst_tg = (const int*)d_in[7];
    const float* Wn_gg = (const float*)d_in[8];
    const float* Ws_gg = (const float*)d_in[9];
    const float* b_gg  = (const float*)d_in[10];
    const float* Wn_gt = (const float*)d_in[11];
    const float* Ws_gt = (const float*)d_in[12];
    const float* b_gt  = (const float*)d_in[13];
    const float* Wn_tg = (const float*)d_in[14];
    const float* Ws_tg = (const float*)d_in[15];
    const float* b_tg  = (const float*)d_in[16];

    const int nE_gg = in_sizes[2];
    const int nE_gt = in_sizes[4];
    const int nE_tg = in_sizes[6];

    float* out_gene  = (float*)d_out;
    float* out_trait = (float*)d_out + (size_t)NG * D;

    // ws layout: agg [100000 x 128] f32 | off [100001] | cur [100000] | sorted [500000]
    float* agg = (float*)d_ws;
    char* p = (char*)d_ws + (size_t)NG * D * sizeof(float);
    int* off    = (int*)p;             p += (size_t)(NG + 1) * sizeof(int);
    int* cur    = (int*)p;             p += (size_t)NG * sizeof(int);
    int* sorted = (int*)p;

    const int gblocks = (NG + ROWS_PER_BLOCK - 1) / ROWS_PER_BLOCK;
    const int tblocks = (NT + ROWS_PER_BLOCK - 1) / ROWS_PER_BLOCK;
    const int tb = 256;

    // self terms first (overwrite out -> deterministic w.r.t. poisoned d_out)
    xw_kernel<<<gblocks, 256, 0, stream>>>(x_gene, NG, Ws_gg, Ws_tg, b_gg, b_tg, out_gene, 0);
    xw_kernel<<<tblocks, 256, 0, stream>>>(x_trait, NT, Ws_gt, nullptr, b_gt, nullptr, out_trait, 0);

    // per etype: CSR build -> gather-mean agg -> out += agg @ Wn
    struct Et { const int* src; const int* dst; int nE; const float* x; int n_dst;
                const float* Wn; float* out; };
    const Et ets[3] = {
        { src_gg, dst_gg, nE_gg, x_gene,  NG, Wn_gg, out_gene  },
        { src_gt, dst_gt, nE_gt, x_gene,  NT, Wn_gt, out_trait },
        { src_tg, dst_tg, nE_tg, x_trait, NG, Wn_tg, out_gene  },
    };
    for (int i = 0; i < 3; ++i) {
        const Et& et = ets[i];
        hipMemsetAsync(cur, 0, (size_t)et.n_dst * sizeof(int), stream);
        deg_kernel<<<(et.nE + tb - 1) / tb, tb, 0, stream>>>(et.dst, cur, et.nE);
        scan_kernel<<<1, 1024, 0, stream>>>(cur, off, et.n_dst);
        hipMemcpyAsync(cur, off, (size_t)et.n_dst * sizeof(int),
                       hipMemcpyDeviceToDevice, stream);
        fill_kernel<<<(et.nE + tb - 1) / tb, tb, 0, stream>>>(et.src, et.dst, cur, sorted, et.nE);
        agg_kernel<<<(et.n_dst + 3) / 4, 256, 0, stream>>>(et.x, off, sorted, agg, et.n_dst);
        xw_kernel<<<(et.n_dst + ROWS_PER_BLOCK - 1) / ROWS_PER_BLOCK, 256, 0, stream>>>(
            agg, et.n_dst, et.Wn, nullptr, nullptr, nullptr, et.out, 1);
    }
}

// Round 3
// 732.629 us; speedup vs baseline: 1.6488x; 1.6488x over previous
//
#include <hip/hip_runtime.h>
#include <hip/hip_bf16.h>

// HeteroGCN: 3x SAGEConv(mean).
// R1: CSR + gather aggregation (no output atomics).
// R2: single-block scan (165us x3) -> hierarchical 3-kernel scan over the
//     concatenated degree array of all 3 etypes (~5us total).

#define D 128
#define NG 100000
#define NT 100000
#define NSEG (NG + NT + NG)   // concatenated dst-node counters: gg | gt | tg

constexpr int ROWS_PER_BLOCK = 32;

// out[row][c] = x[row][:] @ (W1 (+W2)) (+ b1 (+ b2)) ; accumulate ? out += : out =
__global__ __launch_bounds__(256) void xw_kernel(
    const float* __restrict__ x, int n_rows,
    const float* __restrict__ W1, const float* __restrict__ W2,
    const float* __restrict__ b1, const float* __restrict__ b2,
    float* __restrict__ out, int accumulate)
{
    __shared__ float Wl[D][D];                 // 64 KiB
    __shared__ float Xl[ROWS_PER_BLOCK][D];    // 16 KiB
    const int t = threadIdx.x;

    {
        const float4* w1 = (const float4*)W1;
        const float4* w2 = (const float4*)W2;
        float4* wl = (float4*)&Wl[0][0];
        for (int i = t; i < D * D / 4; i += 256) {
            float4 v = w1[i];
            if (w2) { float4 u = w2[i]; v.x += u.x; v.y += u.y; v.z += u.z; v.w += u.w; }
            wl[i] = v;
        }
    }
    const int row0 = blockIdx.x * ROWS_PER_BLOCK;
    const int nrow = min(ROWS_PER_BLOCK, n_rows - row0);
    {
        const float4* xg = (const float4*)(x + (size_t)row0 * D);
        float4* xl = (float4*)&Xl[0][0];
        const int nv = nrow * (D / 4);
        for (int i = t; i < nv; i += 256) xl[i] = xg[i];
    }
    __syncthreads();

    const int cg = t & 31;
    const int rg = t >> 5;
    const int c0 = cg * 4;
    constexpr int R = 4;
    const int rbase = rg * R;

    float4 bv = make_float4(0.f, 0.f, 0.f, 0.f);
    if (b1) { float4 u = *(const float4*)(b1 + c0); bv.x += u.x; bv.y += u.y; bv.z += u.z; bv.w += u.w; }
    if (b2) { float4 u = *(const float4*)(b2 + c0); bv.x += u.x; bv.y += u.y; bv.z += u.z; bv.w += u.w; }

    float acc[R][4];
#pragma unroll
    for (int i = 0; i < R; ++i) {
        acc[i][0] = bv.x; acc[i][1] = bv.y; acc[i][2] = bv.z; acc[i][3] = bv.w;
    }

    for (int k = 0; k < D; k += 4) {
        float4 w0 = *(const float4*)&Wl[k + 0][c0];
        float4 w1 = *(const float4*)&Wl[k + 1][c0];
        float4 w2 = *(const float4*)&Wl[k + 2][c0];
        float4 w3 = *(const float4*)&Wl[k + 3][c0];
#pragma unroll
        for (int i = 0; i < R; ++i) {
            float4 xv = *(const float4*)&Xl[rbase + i][k];
            acc[i][0] += xv.x * w0.x + xv.y * w1.x + xv.z * w2.x + xv.w * w3.x;
            acc[i][1] += xv.x * w0.y + xv.y * w1.y + xv.z * w2.y + xv.w * w3.y;
            acc[i][2] += xv.x * w0.z + xv.y * w1.z + xv.z * w2.z + xv.w * w3.z;
            acc[i][3] += xv.x * w0.w + xv.y * w1.w + xv.z * w2.w + xv.w * w3.w;
        }
    }

#pragma unroll
    for (int i = 0; i < R; ++i) {
        const int r = rbase + i;
        if (r < nrow) {
            float4 v = make_float4(acc[i][0], acc[i][1], acc[i][2], acc[i][3]);
            float* p = out + (size_t)(row0 + r) * D + c0;
            if (accumulate) {
                float4 o = *(const float4*)p;
                v.x += o.x; v.y += o.y; v.z += o.z; v.w += o.w;
            }
            *(float4*)p = v;
        }
    }
}

__global__ __launch_bounds__(256) void deg_kernel(
    const int* __restrict__ dst, int* __restrict__ deg, int nE)
{
    int i = blockIdx.x * blockDim.x + threadIdx.x;
    if (i < nE) atomicAdd(&deg[dst[i]], 1);
}

// ---- hierarchical exclusive scan over NSEG ints: partial -> part-scan -> apply
constexpr int SCAN_TPB = 256;
constexpr int SCAN_EPT = 8;
constexpr int SCAN_EPB = SCAN_TPB * SCAN_EPT;   // 2048
constexpr int SCAN_NB  = (NSEG + SCAN_EPB - 1) / SCAN_EPB;  // 147

__global__ __launch_bounds__(SCAN_TPB) void scan_partial_kernel(
    const int* __restrict__ deg, int* __restrict__ part, int n)
{
    __shared__ int lds[SCAN_TPB];
    const int t = threadIdx.x;
    const int base = blockIdx.x * SCAN_EPB + t * SCAN_EPT;
    int s = 0;
#pragma unroll
    for (int j = 0; j < SCAN_EPT; ++j) {
        int i = base + j;
        if (i < n) s += deg[i];
    }
    lds[t] = s;
    __syncthreads();
    for (int sh = SCAN_TPB / 2; sh > 0; sh >>= 1) {
        if (t < sh) lds[t] += lds[t + sh];
        __syncthreads();
    }
    if (t == 0) part[blockIdx.x] = lds[0];
}

__global__ __launch_bounds__(SCAN_TPB) void scan_parts_kernel(
    int* __restrict__ part, int nblocks)
{
    __shared__ int lds[SCAN_TPB];
    const int t = threadIdx.x;
    const int v = (t < nblocks) ? part[t] : 0;
    lds[t] = v;
    __syncthreads();
    for (int sh = 1; sh < SCAN_TPB; sh <<= 1) {
        int u = (t >= sh) ? lds[t - sh] : 0;
        __syncthreads();
        lds[t] += u;
        __syncthreads();
    }
    if (t < nblocks) part[t] = lds[t] - v;   // exclusive
}

__global__ __launch_bounds__(SCAN_TPB) void scan_apply_kernel(
    const int* __restrict__ deg, const int* __restrict__ part,
    int* __restrict__ off, int n)
{
    __shared__ int lds[SCAN_TPB];
    const int t = threadIdx.x;
    const int base = blockIdx.x * SCAN_EPB + t * SCAN_EPT;
    int loc[SCAN_EPT];
    int s = 0;
#pragma unroll
    for (int j = 0; j < SCAN_EPT; ++j) {
        int i = base + j;
        loc[j] = (i < n) ? deg[i] : 0;
        s += loc[j];
    }
    lds[t] = s;
    __syncthreads();
    for (int sh = 1; sh < SCAN_TPB; sh <<= 1) {
        int u = (t >= sh) ? lds[t - sh] : 0;
        __syncthreads();
        lds[t] += u;
        __syncthreads();
    }
    int run = part[blockIdx.x] + lds[t] - s;   // exclusive prefix for this thread
#pragma unroll
    for (int j = 0; j < SCAN_EPT; ++j) {
        int i = base + j;
        if (i < n) {
            off[i] = run;
            run += loc[j];
            if (i == n - 1) off[n] = run;
        }
    }
}

__global__ __launch_bounds__(256) void fill_kernel(
    const int* __restrict__ src, const int* __restrict__ dst,
    int* __restrict__ cur, int* __restrict__ sorted, int nE)
{
    int e = blockIdx.x * blockDim.x + threadIdx.x;
    if (e < nE) {
        int p = atomicAdd(&cur[dst[e]], 1);
        sorted[p] = src[e];
    }
}

// one wave per dst node: agg[node] = mean over CSR neighbors of x[src]
__global__ __launch_bounds__(256) void agg_kernel(
    const float* __restrict__ x, const int* __restrict__ off,
    const int* __restrict__ sorted, float* __restrict__ agg, int n_dst)
{
    const int node = blockIdx.x * 4 + (threadIdx.x >> 6);
    if (node >= n_dst) return;
    const int lane = threadIdx.x & 63;
    const int s0 = off[node];
    const int s1 = off[node + 1];
    float2 acc = make_float2(0.f, 0.f);
    for (int e = s0; e < s1; ++e) {
        const int s = sorted[e];
        float2 v = *(const float2*)(x + (size_t)s * D + lane * 2);
        acc.x += v.x; acc.y += v.y;
    }
    const float inv = 1.0f / (float)max(s1 - s0, 1);
    *(float2*)(agg + (size_t)node * D + lane * 2) = make_float2(acc.x * inv, acc.y * inv);
}

extern "C" void kernel_launch(void* const* d_in, const int* in_sizes, int n_in,
                              void* d_out, int out_size, void* d_ws, size_t ws_size,
                              hipStream_t stream)
{
    const float* x_gene  = (const float*)d_in[0];
    const float* x_trait = (const float*)d_in[1];
    const int* src_gg = (const int*)d_in[2];
    const int* dst_gg = (const int*)d_in[3];
    const int* src_gt = (const int*)d_in[4];
    const int* dst_gt = (const int*)d_in[5];
    const int* src_tg = (const int*)d_in[6];
    const int* dst_tg = (const int*)d_in[7];
    const float* Wn_gg = (const float*)d_in[8];
    const float* Ws_gg = (const float*)d_in[9];
    const float* b_gg  = (const float*)d_in[10];
    const float* Wn_gt = (const float*)d_in[11];
    const float* Ws_gt = (const float*)d_in[12];
    const float* b_gt  = (const float*)d_in[13];
    const float* Wn_tg = (const float*)d_in[14];
    const float* Ws_tg = (const float*)d_in[15];
    const float* b_tg  = (const float*)d_in[16];

    const int nE_gg = in_sizes[2];
    const int nE_gt = in_sizes[4];
    const int nE_tg = in_sizes[6];
    const int nE_total = nE_gg + nE_gt + nE_tg;

    float* out_gene  = (float*)d_out;
    float* out_trait = (float*)d_out + (size_t)NG * D;

    // ws layout: agg [100000x128] f32 | off [NSEG+1] | cur/deg [NSEG] | part [256] | sorted [nE_total]
    float* agg = (float*)d_ws;
    char* p = (char*)d_ws + (size_t)NG * D * sizeof(float);
    int* off    = (int*)p;  p += (size_t)(NSEG + 1) * sizeof(int);
    int* cur    = (int*)p;  p += (size_t)NSEG * sizeof(int);
    int* part   = (int*)p;  p += 256 * sizeof(int);
    int* sorted = (int*)p;

    const int tb = 256;
    const int gblocks = (NG + ROWS_PER_BLOCK - 1) / ROWS_PER_BLOCK;
    const int tblocks = (NT + ROWS_PER_BLOCK - 1) / ROWS_PER_BLOCK;

    // self terms (overwrite out)
    xw_kernel<<<gblocks, 256, 0, stream>>>(x_gene, NG, Ws_gg, Ws_tg, b_gg, b_tg, out_gene, 0);
    xw_kernel<<<tblocks, 256, 0, stream>>>(x_trait, NT, Ws_gt, nullptr, b_gt, nullptr, out_trait, 0);

    // 1) degree histograms for all etypes into one concatenated array (cur doubles as deg)
    hipMemsetAsync(cur, 0, (size_t)NSEG * sizeof(int), stream);
    deg_kernel<<<(nE_gg + tb - 1) / tb, tb, 0, stream>>>(dst_gg, cur, nE_gg);
    deg_kernel<<<(nE_gt + tb - 1) / tb, tb, 0, stream>>>(dst_gt, cur + NG, nE_gt);
    deg_kernel<<<(nE_tg + tb - 1) / tb, tb, 0, stream>>>(dst_tg, cur + NG + NT, nE_tg);

    // 2) one hierarchical exclusive scan over all NSEG counters
    scan_partial_kernel<<<SCAN_NB, SCAN_TPB, 0, stream>>>(cur, part, NSEG);
    scan_parts_kernel<<<1, SCAN_TPB, 0, stream>>>(part, SCAN_NB);
    scan_apply_kernel<<<SCAN_NB, SCAN_TPB, 0, stream>>>(cur, part, off, NSEG);

    // 3) cursors = copy of offsets; fill CSR (positions are global across etypes)
    hipMemcpyAsync(cur, off, (size_t)NSEG * sizeof(int), hipMemcpyDeviceToDevice, stream);
    fill_kernel<<<(nE_gg + tb - 1) / tb, tb, 0, stream>>>(src_gg, dst_gg, cur, sorted, nE_gg);
    fill_kernel<<<(nE_gt + tb - 1) / tb, tb, 0, stream>>>(src_gt, dst_gt, cur + NG, sorted, nE_gt);
    fill_kernel<<<(nE_tg + tb - 1) / tb, tb, 0, stream>>>(src_tg, dst_tg, cur + NG + NT, sorted, nE_tg);

    // 4) per etype: gather-mean agg, then out += agg @ Wn
    // gg: dst=gene
    agg_kernel<<<(NG + 3) / 4, 256, 0, stream>>>(x_gene, off, sorted, agg, NG);
    xw_kernel<<<gblocks, 256, 0, stream>>>(agg, NG, Wn_gg, nullptr, nullptr, nullptr, out_gene, 1);
    // gt: dst=trait
    agg_kernel<<<(NT + 3) / 4, 256, 0, stream>>>(x_gene, off + NG, sorted, agg, NT);
    xw_kernel<<<tblocks, 256, 0, stream>>>(agg, NT, Wn_gt, nullptr, nullptr, nullptr, out_trait, 1);
    // tg: dst=gene
    agg_kernel<<<(NG + 3) / 4, 256, 0, stream>>>(x_trait, off + NG + NT, sorted, agg, NG);
    xw_kernel<<<gblocks, 256, 0, stream>>>(agg, NG, Wn_tg, nullptr, nullptr, nullptr, out_gene, 1);
}

// Round 4
// 422.606 us; speedup vs baseline: 2.8584x; 1.7336x over previous
//
#include <hip/hip_runtime.h>
#include <hip/hip_bf16.h>

// HeteroGCN: 3x SAGEConv(mean).
// R1: CSR + gather aggregation (no output atomics).
// R2: hierarchical scan (one scan over all 3 etypes' degree counters).
// R3: bf16 MFMA GEMM with K-concatenation:
//     out_gene  = [x_gene | agg_gg | agg_tg] @ [Ws_gg+Ws_tg; Wn_gg; Wn_tg] + b_gg+b_tg
//     out_trait = [x_trait | agg_gt]         @ [Ws_gt; Wn_gt]             + b_gt
//     Weights pre-packed to fragment order; agg emits bf16; single overwrite pass per output.

#define D 128
#define NG 100000
#define NT 100000
#define NSEG (NG + NT + NG)   // concatenated dst-node counters: gg | gt | tg

typedef __bf16 bf16x8 __attribute__((ext_vector_type(8)));
typedef float f32x16 __attribute__((ext_vector_type(16)));

// ---------------- weight pack + bias fold ----------------
// Fragment order for v_mfma_f32_32x32x16_bf16 B-operand:
// slot (kt, nt, lane, j) holds W[kt*16 + (lane>>5)*8 + j][nt*32 + (lane&31)]
// Gene: kt in [0,24) over [Ws_gg+Ws_tg ; Wn_gg ; Wn_tg]; Trait: kt in [0,16) over [Ws_gt ; Wn_gt].
__global__ __launch_bounds__(256) void prep_kernel(
    const float* __restrict__ Ws_gg, const float* __restrict__ Ws_tg,
    const float* __restrict__ Wn_gg, const float* __restrict__ Wn_tg,
    const float* __restrict__ Ws_gt, const float* __restrict__ Wn_gt,
    const float* __restrict__ b_gg, const float* __restrict__ b_tg,
    const float* __restrict__ b_gt,
    unsigned short* __restrict__ WpG, unsigned short* __restrict__ WpT,
    float* __restrict__ biasG, float* __restrict__ biasT)
{
    const int gid = blockIdx.x * 256 + threadIdx.x;
    if (gid < 6144) {                       // gene pack: 24 kt * 4 nt * 64 lanes
        const int lane = gid & 63, nt = (gid >> 6) & 3, kt = gid >> 8;
        const int n = nt * 32 + (lane & 31);
        const int kb = kt * 16 + (lane >> 5) * 8;
        unsigned int pk[4];
#pragma unroll
        for (int jj = 0; jj < 4; ++jj) {
            unsigned int w2 = 0;
#pragma unroll
            for (int h = 0; h < 2; ++h) {
                const int k = kb + jj * 2 + h;
                float w;
                if (k < 128)      w = Ws_gg[k * D + n] + Ws_tg[k * D + n];
                else if (k < 256) w = Wn_gg[(k - 128) * D + n];
                else              w = Wn_tg[(k - 256) * D + n];
                const unsigned short b = __builtin_bit_cast(unsigned short, (__bf16)w);
                w2 |= ((unsigned int)b) << (16 * h);
            }
            pk[jj] = w2;
        }
        *(uint4*)(WpG + (size_t)gid * 8) = make_uint4(pk[0], pk[1], pk[2], pk[3]);
    } else if (gid < 6144 + 4096) {         // trait pack: 16 kt * 4 nt * 64 lanes
        const int g = gid - 6144;
        const int lane = g & 63, nt = (g >> 6) & 3, kt = g >> 8;
        const int n = nt * 32 + (lane & 31);
        const int kb = kt * 16 + (lane >> 5) * 8;
        unsigned int pk[4];
#pragma unroll
        for (int jj = 0; jj < 4; ++jj) {
            unsigned int w2 = 0;
#pragma unroll
            for (int h = 0; h < 2; ++h) {
                const int k = kb + jj * 2 + h;
                const float w = (k < 128) ? Ws_gt[k * D + n] : Wn_gt[(k - 128) * D + n];
                const unsigned short b = __builtin_bit_cast(unsigned short, (__bf16)w);
                w2 |= ((unsigned int)b) << (16 * h);
            }
            pk[jj] = w2;
        }
        *(uint4*)(WpT + (size_t)g * 8) = make_uint4(pk[0], pk[1], pk[2], pk[3]);
    } else if (gid < 6144 + 4096 + 128) {
        const int i = gid - (6144 + 4096);
        biasG[i] = b_gg[i] + b_tg[i];
    } else if (gid < 6144 + 4096 + 256) {
        const int i = gid - (6144 + 4096 + 128);
        biasT[i] = b_gt[i];
    }
}

// ---------------- CSR build ----------------
__global__ __launch_bounds__(256) void deg_kernel(
    const int* __restrict__ dst, int* __restrict__ deg, int nE)
{
    int i = blockIdx.x * blockDim.x + threadIdx.x;
    if (i < nE) atomicAdd(&deg[dst[i]], 1);
}

constexpr int SCAN_TPB = 256;
constexpr int SCAN_EPT = 8;
constexpr int SCAN_EPB = SCAN_TPB * SCAN_EPT;               // 2048
constexpr int SCAN_NB  = (NSEG + SCAN_EPB - 1) / SCAN_EPB;  // 147

__global__ __launch_bounds__(SCAN_TPB) void scan_partial_kernel(
    const int* __restrict__ deg, int* __restrict__ part, int n)
{
    __shared__ int lds[SCAN_TPB];
    const int t = threadIdx.x;
    const int base = blockIdx.x * SCAN_EPB + t * SCAN_EPT;
    int s = 0;
#pragma unroll
    for (int j = 0; j < SCAN_EPT; ++j) {
        int i = base + j;
        if (i < n) s += deg[i];
    }
    lds[t] = s;
    __syncthreads();
    for (int sh = SCAN_TPB / 2; sh > 0; sh >>= 1) {
        if (t < sh) lds[t] += lds[t + sh];
        __syncthreads();
    }
    if (t == 0) part[blockIdx.x] = lds[0];
}

__global__ __launch_bounds__(SCAN_TPB) void scan_parts_kernel(
    int* __restrict__ part, int nblocks)
{
    __shared__ int lds[SCAN_TPB];
    const int t = threadIdx.x;
    const int v = (t < nblocks) ? part[t] : 0;
    lds[t] = v;
    __syncthreads();
    for (int sh = 1; sh < SCAN_TPB; sh <<= 1) {
        int u = (t >= sh) ? lds[t - sh] : 0;
        __syncthreads();
        lds[t] += u;
        __syncthreads();
    }
    if (t < nblocks) part[t] = lds[t] - v;
}

__global__ __launch_bounds__(SCAN_TPB) void scan_apply_kernel(
    const int* __restrict__ deg, const int* __restrict__ part,
    int* __restrict__ off, int n)
{
    __shared__ int lds[SCAN_TPB];
    const int t = threadIdx.x;
    const int base = blockIdx.x * SCAN_EPB + t * SCAN_EPT;
    int loc[SCAN_EPT];
    int s = 0;
#pragma unroll
    for (int j = 0; j < SCAN_EPT; ++j) {
        int i = base + j;
        loc[j] = (i < n) ? deg[i] : 0;
        s += loc[j];
    }
    lds[t] = s;
    __syncthreads();
    for (int sh = 1; sh < SCAN_TPB; sh <<= 1) {
        int u = (t >= sh) ? lds[t - sh] : 0;
        __syncthreads();
        lds[t] += u;
        __syncthreads();
    }
    int run = part[blockIdx.x] + lds[t] - s;
#pragma unroll
    for (int j = 0; j < SCAN_EPT; ++j) {
        int i = base + j;
        if (i < n) {
            off[i] = run;
            run += loc[j];
            if (i == n - 1) off[n] = run;
        }
    }
}

__global__ __launch_bounds__(256) void fill_kernel(
    const int* __restrict__ src, const int* __restrict__ dst,
    int* __restrict__ cur, int* __restrict__ sorted, int nE)
{
    int e = blockIdx.x * blockDim.x + threadIdx.x;
    if (e < nE) {
        int p = atomicAdd(&cur[dst[e]], 1);
        sorted[p] = src[e];
    }
}

// ---------------- aggregation (fp32 gather -> bf16 mean) ----------------
__global__ __launch_bounds__(256) void agg_kernel(
    const float* __restrict__ x, const int* __restrict__ off,
    const int* __restrict__ sorted, unsigned short* __restrict__ agg, int n_dst)
{
    const int node = blockIdx.x * 4 + (threadIdx.x >> 6);
    if (node >= n_dst) return;
    const int lane = threadIdx.x & 63;
    const int s0 = off[node];
    const int s1 = off[node + 1];
    float ax = 0.f, ay = 0.f;
    for (int e = s0; e < s1; ++e) {
        const float2 v = *(const float2*)(x + (size_t)sorted[e] * D + lane * 2);
        ax += v.x; ay += v.y;
    }
    const float inv = 1.0f / (float)max(s1 - s0, 1);
    const unsigned short h0 = __builtin_bit_cast(unsigned short, (__bf16)(ax * inv));
    const unsigned short h1 = __builtin_bit_cast(unsigned short, (__bf16)(ay * inv));
    *(unsigned int*)(agg + (size_t)node * D + lane * 2) =
        ((unsigned int)h1 << 16) | (unsigned int)h0;
}

// ---------------- MFMA GEMM: out[m][n] = concat_A[m][:] @ Wcat + bias ----------------
// 1024 threads = 16 waves; wave handles one 32-row tile. Per source s: stage its
// 32 KB fragment-packed W slice in LDS, then 8 kt x 4 nt MFMAs.
// Operand-swapped mfma(Wfrag, xfrag): lane col = m, regs = n -> float4 stores.
template<int NSRC>
__global__ __launch_bounds__(1024) void gemm_kernel(
    const float* __restrict__ Aself,
    const unsigned short* __restrict__ Ag1,
    const unsigned short* __restrict__ Ag2,
    const unsigned short* __restrict__ Wpack,
    const float* __restrict__ bias,
    float* __restrict__ out, int M)
{
    __shared__ unsigned short WL[8 * 4 * 64 * 8];   // 32 KiB: one source slice
    const int t = threadIdx.x;
    const int wid = t >> 6, lane = t & 63;
    const int lm = lane & 31, l5 = lane >> 5;
    const int tiles = (M + 31) >> 5;
    const int tile = blockIdx.x * 16 + wid;
    const bool active = tile < tiles;
    const int m = tile * 32 + lm;

    f32x16 acc[4];
    if (active) {
#pragma unroll
        for (int nt = 0; nt < 4; ++nt) {
#pragma unroll
            for (int q = 0; q < 4; ++q) {
                const float4 bq = *(const float4*)&bias[nt * 32 + 4 * l5 + 8 * q];
                acc[nt][4 * q + 0] = bq.x; acc[nt][4 * q + 1] = bq.y;
                acc[nt][4 * q + 2] = bq.z; acc[nt][4 * q + 3] = bq.w;
            }
        }
    }

    const uint4* wg = (const uint4*)Wpack;
    uint4* wl = (uint4*)WL;

    for (int s = 0; s < NSRC; ++s) {
        __syncthreads();
        wl[t]        = wg[(size_t)s * 2048 + t];
        wl[t + 1024] = wg[(size_t)s * 2048 + t + 1024];
        __syncthreads();
        if (active) {
            if (s == 0) {
                const float* ar = Aself + (size_t)m * D;
#pragma unroll
                for (int kt = 0; kt < 8; ++kt) {
                    const float4 f0 = *(const float4*)&ar[kt * 16 + l5 * 8];
                    const float4 f1 = *(const float4*)&ar[kt * 16 + l5 * 8 + 4];
                    bf16x8 a;
                    a[0] = (__bf16)f0.x; a[1] = (__bf16)f0.y; a[2] = (__bf16)f0.z; a[3] = (__bf16)f0.w;
                    a[4] = (__bf16)f1.x; a[5] = (__bf16)f1.y; a[6] = (__bf16)f1.z; a[7] = (__bf16)f1.w;
#pragma unroll
                    for (int nt = 0; nt < 4; ++nt) {
                        const bf16x8 b = *(const bf16x8*)&WL[((kt * 4 + nt) * 64 + lane) * 8];
                        acc[nt] = __builtin_amdgcn_mfma_f32_32x32x16_bf16(b, a, acc[nt], 0, 0, 0);
                    }
                }
            } else {
                const unsigned short* ag = (s == 1) ? Ag1 : Ag2;
                const unsigned short* ar = ag + (size_t)m * D;
#pragma unroll
                for (int kt = 0; kt < 8; ++kt) {
                    const bf16x8 a = *(const bf16x8*)&ar[kt * 16 + l5 * 8];
#pragma unroll
                    for (int nt = 0; nt < 4; ++nt) {
                        const bf16x8 b = *(const bf16x8*)&WL[((kt * 4 + nt) * 64 + lane) * 8];
                        acc[nt] = __builtin_amdgcn_mfma_f32_32x32x16_bf16(b, a, acc[nt], 0, 0, 0);
                    }
                }
            }
        }
    }

    if (active) {
        float* orow = out + (size_t)m * D;
#pragma unroll
        for (int nt = 0; nt < 4; ++nt) {
            float* p = orow + nt * 32 + 4 * l5;
            *(float4*)(p + 0)  = make_float4(acc[nt][0],  acc[nt][1],  acc[nt][2],  acc[nt][3]);
            *(float4*)(p + 8)  = make_float4(acc[nt][4],  acc[nt][5],  acc[nt][6],  acc[nt][7]);
            *(float4*)(p + 16) = make_float4(acc[nt][8],  acc[nt][9],  acc[nt][10], acc[nt][11]);
            *(float4*)(p + 24) = make_float4(acc[nt][12], acc[nt][13], acc[nt][14], acc[nt][15]);
        }
    }
}

extern "C" void kernel_launch(void* const* d_in, const int* in_sizes, int n_in,
                              void* d_out, int out_size, void* d_ws, size_t ws_size,
                              hipStream_t stream)
{
    const float* x_gene  = (const float*)d_in[0];
    const float* x_trait = (const float*)d_in[1];
    const int* src_gg = (const int*)d_in[2];
    const int* dst_gg = (const int*)d_in[3];
    const int* src_gt = (const int*)d_in[4];
    const int* dst_gt = (const int*)d_in[5];
    const int* src_tg = (const int*)d_in[6];
    const int* dst_tg = (const int*)d_in[7];
    const float* Wn_gg = (const float*)d_in[8];
    const float* Ws_gg = (const float*)d_in[9];
    const float* b_gg  = (const float*)d_in[10];
    const float* Wn_gt = (const float*)d_in[11];
    const float* Ws_gt = (const float*)d_in[12];
    const float* b_gt  = (const float*)d_in[13];
    const float* Wn_tg = (const float*)d_in[14];
    const float* Ws_tg = (const float*)d_in[15];
    const float* b_tg  = (const float*)d_in[16];

    const int nE_gg = in_sizes[2];
    const int nE_gt = in_sizes[4];
    const int nE_tg = in_sizes[6];

    float* out_gene  = (float*)d_out;
    float* out_trait = (float*)d_out + (size_t)NG * D;

    // ws: aggA bf16 [NG*D] | aggB bf16 [NG*D] | WpG (96KB) | WpT (64KB) | biasG | biasT |
    //     off [NSEG+1] | cur [NSEG] | part [256] | sorted [nE_total]
    unsigned short* aggA = (unsigned short*)d_ws;
    unsigned short* aggB = aggA + (size_t)NG * D;
    char* p = (char*)(aggB + (size_t)NG * D);
    unsigned short* WpG = (unsigned short*)p;  p += 24 * 4 * 64 * 8 * sizeof(unsigned short);
    unsigned short* WpT = (unsigned short*)p;  p += 16 * 4 * 64 * 8 * sizeof(unsigned short);
    float* biasG = (float*)p;                  p += D * sizeof(float);
    float* biasT = (float*)p;                  p += D * sizeof(float);
    int* off    = (int*)p;                     p += (size_t)(NSEG + 1) * sizeof(int);
    int* cur    = (int*)p;                     p += (size_t)NSEG * sizeof(int);
    int* part   = (int*)p;                     p += 256 * sizeof(int);
    int* sorted = (int*)p;

    const int tb = 256;

    // weights pack + bias fold (independent of graph work)
    prep_kernel<<<41, 256, 0, stream>>>(Ws_gg, Ws_tg, Wn_gg, Wn_tg, Ws_gt, Wn_gt,
                                        b_gg, b_tg, b_gt, WpG, WpT, biasG, biasT);

    // CSR build (concatenated over etypes)
    hipMemsetAsync(cur, 0, (size_t)NSEG * sizeof(int), stream);
    deg_kernel<<<(nE_gg + tb - 1) / tb, tb, 0, stream>>>(dst_gg, cur, nE_gg);
    deg_kernel<<<(nE_gt + tb - 1) / tb, tb, 0, stream>>>(dst_gt, cur + NG, nE_gt);
    deg_kernel<<<(nE_tg + tb - 1) / tb, tb, 0, stream>>>(dst_tg, cur + NG + NT, nE_tg);

    scan_partial_kernel<<<SCAN_NB, SCAN_TPB, 0, stream>>>(cur, part, NSEG);
    scan_parts_kernel<<<1, SCAN_TPB, 0, stream>>>(part, SCAN_NB);
    scan_apply_kernel<<<SCAN_NB, SCAN_TPB, 0, stream>>>(cur, part, off, NSEG);

    hipMemcpyAsync(cur, off, (size_t)NSEG * sizeof(int), hipMemcpyDeviceToDevice, stream);
    fill_kernel<<<(nE_gg + tb - 1) / tb, tb, 0, stream>>>(src_gg, dst_gg, cur, sorted, nE_gg);
    fill_kernel<<<(nE_gt + tb - 1) / tb, tb, 0, stream>>>(src_gt, dst_gt, cur + NG, sorted, nE_gt);
    fill_kernel<<<(nE_tg + tb - 1) / tb, tb, 0, stream>>>(src_tg, dst_tg, cur + NG + NT, sorted, nE_tg);

    // aggregate (bf16 out), then one overwrite GEMM per node set
    const int gemm_blocks = ((NG + 31) / 32 + 15) / 16;   // 196 for 100k rows

    agg_kernel<<<(NG + 3) / 4, 256, 0, stream>>>(x_gene,  off,           sorted, aggA, NG); // gg
    agg_kernel<<<(NG + 3) / 4, 256, 0, stream>>>(x_trait, off + NG + NT, sorted, aggB, NG); // tg
    gemm_kernel<3><<<gemm_blocks, 1024, 0, stream>>>(x_gene, aggA, aggB, WpG, biasG, out_gene, NG);

    agg_kernel<<<(NT + 3) / 4, 256, 0, stream>>>(x_gene,  off + NG,      sorted, aggA, NT); // gt
    gemm_kernel<2><<<gemm_blocks, 1024, 0, stream>>>(x_trait, aggA, nullptr, WpT, biasT, out_trait, NT);
}

// Round 5
// 369.684 us; speedup vs baseline: 3.2676x; 1.1432x over previous
//
#include <hip/hip_runtime.h>
#include <hip/hip_bf16.h>

// HeteroGCN: 3x SAGEConv(mean).
// R1: CSR + gather aggregation (no output atomics).
// R2: hierarchical scan over concatenated degree counters.
// R3: bf16 MFMA GEMM with K-concatenation, packed weights, single pass per output.
// R4: gather unroll x4 (4 row-loads in flight) + bf16 feature table for gene
//     (halves gather fetch for gg/gt and gene GEMM self-term).

#define D 128
#define NG 100000
#define NT 100000
#define NSEG (NG + NT + NG)   // concatenated dst-node counters: gg | gt | tg

typedef __bf16 bf16x8 __attribute__((ext_vector_type(8)));
typedef float f32x16 __attribute__((ext_vector_type(16)));

static __device__ __forceinline__ unsigned short f2bf(float f) {
    return __builtin_bit_cast(unsigned short, (__bf16)f);
}
static __device__ __forceinline__ float bflo(unsigned int v) {
    return __builtin_bit_cast(float, v << 16);
}
static __device__ __forceinline__ float bfhi(unsigned int v) {
    return __builtin_bit_cast(float, v & 0xffff0000u);
}

// ---------------- fp32 -> bf16 feature table ----------------
__global__ __launch_bounds__(256) void cvt_kernel(
    const float* __restrict__ x, unsigned short* __restrict__ xb, int n8)
{
    const int i = blockIdx.x * 256 + threadIdx.x;
    if (i >= n8) return;
    const float4 f0 = ((const float4*)x)[i * 2];
    const float4 f1 = ((const float4*)x)[i * 2 + 1];
    uint4 o;
    o.x = (unsigned int)f2bf(f0.x) | ((unsigned int)f2bf(f0.y) << 16);
    o.y = (unsigned int)f2bf(f0.z) | ((unsigned int)f2bf(f0.w) << 16);
    o.z = (unsigned int)f2bf(f1.x) | ((unsigned int)f2bf(f1.y) << 16);
    o.w = (unsigned int)f2bf(f1.z) | ((unsigned int)f2bf(f1.w) << 16);
    ((uint4*)xb)[i] = o;
}

// ---------------- weight pack + bias fold ----------------
// B-frag slot (kt, nt, lane, j) holds W[kt*16 + (lane>>5)*8 + j][nt*32 + (lane&31)]
__global__ __launch_bounds__(256) void prep_kernel(
    const float* __restrict__ Ws_gg, const float* __restrict__ Ws_tg,
    const float* __restrict__ Wn_gg, const float* __restrict__ Wn_tg,
    const float* __restrict__ Ws_gt, const float* __restrict__ Wn_gt,
    const float* __restrict__ b_gg, const float* __restrict__ b_tg,
    const float* __restrict__ b_gt,
    unsigned short* __restrict__ WpG, unsigned short* __restrict__ WpT,
    float* __restrict__ biasG, float* __restrict__ biasT)
{
    const int gid = blockIdx.x * 256 + threadIdx.x;
    if (gid < 6144) {                       // gene pack: 24 kt * 4 nt * 64 lanes
        const int lane = gid & 63, nt = (gid >> 6) & 3, kt = gid >> 8;
        const int n = nt * 32 + (lane & 31);
        const int kb = kt * 16 + (lane >> 5) * 8;
        unsigned int pk[4];
#pragma unroll
        for (int jj = 0; jj < 4; ++jj) {
            unsigned int w2 = 0;
#pragma unroll
            for (int h = 0; h < 2; ++h) {
                const int k = kb + jj * 2 + h;
                float w;
                if (k < 128)      w = Ws_gg[k * D + n] + Ws_tg[k * D + n];
                else if (k < 256) w = Wn_gg[(k - 128) * D + n];
                else              w = Wn_tg[(k - 256) * D + n];
                w2 |= ((unsigned int)f2bf(w)) << (16 * h);
            }
            pk[jj] = w2;
        }
        *(uint4*)(WpG + (size_t)gid * 8) = make_uint4(pk[0], pk[1], pk[2], pk[3]);
    } else if (gid < 6144 + 4096) {         // trait pack: 16 kt * 4 nt * 64 lanes
        const int g = gid - 6144;
        const int lane = g & 63, nt = (g >> 6) & 3, kt = g >> 8;
        const int n = nt * 32 + (lane & 31);
        const int kb = kt * 16 + (lane >> 5) * 8;
        unsigned int pk[4];
#pragma unroll
        for (int jj = 0; jj < 4; ++jj) {
            unsigned int w2 = 0;
#pragma unroll
            for (int h = 0; h < 2; ++h) {
                const int k = kb + jj * 2 + h;
                const float w = (k < 128) ? Ws_gt[k * D + n] : Wn_gt[(k - 128) * D + n];
                w2 |= ((unsigned int)f2bf(w)) << (16 * h);
            }
            pk[jj] = w2;
        }
        *(uint4*)(WpT + (size_t)g * 8) = make_uint4(pk[0], pk[1], pk[2], pk[3]);
    } else if (gid < 6144 + 4096 + 128) {
        const int i = gid - (6144 + 4096);
        biasG[i] = b_gg[i] + b_tg[i];
    } else if (gid < 6144 + 4096 + 256) {
        const int i = gid - (6144 + 4096 + 128);
        biasT[i] = b_gt[i];
    }
}

// ---------------- CSR build ----------------
__global__ __launch_bounds__(256) void deg_kernel(
    const int* __restrict__ dst, int* __restrict__ deg, int nE)
{
    int i = blockIdx.x * blockDim.x + threadIdx.x;
    if (i < nE) atomicAdd(&deg[dst[i]], 1);
}

constexpr int SCAN_TPB = 256;
constexpr int SCAN_EPT = 8;
constexpr int SCAN_EPB = SCAN_TPB * SCAN_EPT;               // 2048
constexpr int SCAN_NB  = (NSEG + SCAN_EPB - 1) / SCAN_EPB;  // 147

__global__ __launch_bounds__(SCAN_TPB) void scan_partial_kernel(
    const int* __restrict__ deg, int* __restrict__ part, int n)
{
    __shared__ int lds[SCAN_TPB];
    const int t = threadIdx.x;
    const int base = blockIdx.x * SCAN_EPB + t * SCAN_EPT;
    int s = 0;
#pragma unroll
    for (int j = 0; j < SCAN_EPT; ++j) {
        int i = base + j;
        if (i < n) s += deg[i];
    }
    lds[t] = s;
    __syncthreads();
    for (int sh = SCAN_TPB / 2; sh > 0; sh >>= 1) {
        if (t < sh) lds[t] += lds[t + sh];
        __syncthreads();
    }
    if (t == 0) part[blockIdx.x] = lds[0];
}

__global__ __launch_bounds__(SCAN_TPB) void scan_parts_kernel(
    int* __restrict__ part, int nblocks)
{
    __shared__ int lds[SCAN_TPB];
    const int t = threadIdx.x;
    const int v = (t < nblocks) ? part[t] : 0;
    lds[t] = v;
    __syncthreads();
    for (int sh = 1; sh < SCAN_TPB; sh <<= 1) {
        int u = (t >= sh) ? lds[t - sh] : 0;
        __syncthreads();
        lds[t] += u;
        __syncthreads();
    }
    if (t < nblocks) part[t] = lds[t] - v;
}

__global__ __launch_bounds__(SCAN_TPB) void scan_apply_kernel(
    const int* __restrict__ deg, const int* __restrict__ part,
    int* __restrict__ off, int n)
{
    __shared__ int lds[SCAN_TPB];
    const int t = threadIdx.x;
    const int base = blockIdx.x * SCAN_EPB + t * SCAN_EPT;
    int loc[SCAN_EPT];
    int s = 0;
#pragma unroll
    for (int j = 0; j < SCAN_EPT; ++j) {
        int i = base + j;
        loc[j] = (i < n) ? deg[i] : 0;
        s += loc[j];
    }
    lds[t] = s;
    __syncthreads();
    for (int sh = 1; sh < SCAN_TPB; sh <<= 1) {
        int u = (t >= sh) ? lds[t - sh] : 0;
        __syncthreads();
        lds[t] += u;
        __syncthreads();
    }
    int run = part[blockIdx.x] + lds[t] - s;
#pragma unroll
    for (int j = 0; j < SCAN_EPT; ++j) {
        int i = base + j;
        if (i < n) {
            off[i] = run;
            run += loc[j];
            if (i == n - 1) off[n] = run;
        }
    }
}

__global__ __launch_bounds__(256) void fill_kernel(
    const int* __restrict__ src, const int* __restrict__ dst,
    int* __restrict__ cur, int* __restrict__ sorted, int nE)
{
    int e = blockIdx.x * blockDim.x + threadIdx.x;
    if (e < nE) {
        int p = atomicAdd(&cur[dst[e]], 1);
        sorted[p] = src[e];
    }
}

// ---------------- aggregation: mean of gathered rows -> bf16 ----------------
// one wave per dst node, lane covers 2 cols; edge loop unrolled x4 so 4
// independent row-loads are in flight.
template<bool BF16SRC>
__global__ __launch_bounds__(256) void agg_kernel(
    const void* __restrict__ xsrc, const int* __restrict__ off,
    const int* __restrict__ sorted, unsigned short* __restrict__ agg, int n_dst)
{
    const int node = blockIdx.x * 4 + (threadIdx.x >> 6);
    if (node >= n_dst) return;
    const int lane = threadIdx.x & 63;
    const int s0 = off[node];
    const int s1 = off[node + 1];
    float ax = 0.f, ay = 0.f;
    int e = s0;
    if constexpr (BF16SRC) {
        const unsigned short* xb = (const unsigned short*)xsrc;
        for (; e + 3 < s1; e += 4) {
            const int i0 = sorted[e], i1 = sorted[e + 1], i2 = sorted[e + 2], i3 = sorted[e + 3];
            const unsigned int v0 = *(const unsigned int*)(xb + (size_t)i0 * D + lane * 2);
            const unsigned int v1 = *(const unsigned int*)(xb + (size_t)i1 * D + lane * 2);
            const unsigned int v2 = *(const unsigned int*)(xb + (size_t)i2 * D + lane * 2);
            const unsigned int v3 = *(const unsigned int*)(xb + (size_t)i3 * D + lane * 2);
            ax += bflo(v0) + bflo(v1) + bflo(v2) + bflo(v3);
            ay += bfhi(v0) + bfhi(v1) + bfhi(v2) + bfhi(v3);
        }
        for (; e < s1; ++e) {
            const unsigned int v = *(const unsigned int*)(xb + (size_t)sorted[e] * D + lane * 2);
            ax += bflo(v); ay += bfhi(v);
        }
    } else {
        const float* x = (const float*)xsrc;
        for (; e + 3 < s1; e += 4) {
            const int i0 = sorted[e], i1 = sorted[e + 1], i2 = sorted[e + 2], i3 = sorted[e + 3];
            const float2 v0 = *(const float2*)(x + (size_t)i0 * D + lane * 2);
            const float2 v1 = *(const float2*)(x + (size_t)i1 * D + lane * 2);
            const float2 v2 = *(const float2*)(x + (size_t)i2 * D + lane * 2);
            const float2 v3 = *(const float2*)(x + (size_t)i3 * D + lane * 2);
            ax += v0.x + v1.x + v2.x + v3.x;
            ay += v0.y + v1.y + v2.y + v3.y;
        }
        for (; e < s1; ++e) {
            const float2 v = *(const float2*)(x + (size_t)sorted[e] * D + lane * 2);
            ax += v.x; ay += v.y;
        }
    }
    const float inv = 1.0f / (float)max(s1 - s0, 1);
    *(unsigned int*)(agg + (size_t)node * D + lane * 2) =
        (unsigned int)f2bf(ax * inv) | ((unsigned int)f2bf(ay * inv) << 16);
}

// ---------------- MFMA GEMM: out[m][n] = concat_A[m][:] @ Wcat + bias ----------------
// 16 waves; wave = one 32-row tile. Operand-swapped mfma(Wfrag, xfrag).
template<int NSRC, bool SELF_F32>
__global__ __launch_bounds__(1024) void gemm_kernel(
    const void* __restrict__ A0,
    const unsigned short* __restrict__ Ag1,
    const unsigned short* __restrict__ Ag2,
    const unsigned short* __restrict__ Wpack,
    const float* __restrict__ bias,
    float* __restrict__ out, int M)
{
    __shared__ unsigned short WL[8 * 4 * 64 * 8];   // 32 KiB: one source slice
    const int t = threadIdx.x;
    const int wid = t >> 6, lane = t & 63;
    const int lm = lane & 31, l5 = lane >> 5;
    const int tiles = (M + 31) >> 5;
    const int tile = blockIdx.x * 16 + wid;
    const bool active = tile < tiles;
    const int m = tile * 32 + lm;

    f32x16 acc[4];
    if (active) {
#pragma unroll
        for (int nt = 0; nt < 4; ++nt) {
#pragma unroll
            for (int q = 0; q < 4; ++q) {
                const float4 bq = *(const float4*)&bias[nt * 32 + 4 * l5 + 8 * q];
                acc[nt][4 * q + 0] = bq.x; acc[nt][4 * q + 1] = bq.y;
                acc[nt][4 * q + 2] = bq.z; acc[nt][4 * q + 3] = bq.w;
            }
        }
    }

    const uint4* wg = (const uint4*)Wpack;
    uint4* wl = (uint4*)WL;

    for (int s = 0; s < NSRC; ++s) {
        __syncthreads();
        wl[t]        = wg[(size_t)s * 2048 + t];
        wl[t + 1024] = wg[(size_t)s * 2048 + t + 1024];
        __syncthreads();
        if (active) {
            if (s == 0 && SELF_F32) {
                const float* ar = (const float*)A0 + (size_t)m * D;
#pragma unroll
                for (int kt = 0; kt < 8; ++kt) {
                    const float4 f0 = *(const float4*)&ar[kt * 16 + l5 * 8];
                    const float4 f1 = *(const float4*)&ar[kt * 16 + l5 * 8 + 4];
                    bf16x8 a;
                    a[0] = (__bf16)f0.x; a[1] = (__bf16)f0.y; a[2] = (__bf16)f0.z; a[3] = (__bf16)f0.w;
                    a[4] = (__bf16)f1.x; a[5] = (__bf16)f1.y; a[6] = (__bf16)f1.z; a[7] = (__bf16)f1.w;
#pragma unroll
                    for (int nt = 0; nt < 4; ++nt) {
                        const bf16x8 b = *(const bf16x8*)&WL[((kt * 4 + nt) * 64 + lane) * 8];
                        acc[nt] = __builtin_amdgcn_mfma_f32_32x32x16_bf16(b, a, acc[nt], 0, 0, 0);
                    }
                }
            } else {
                const unsigned short* ag =
                    (s == 0) ? (const unsigned short*)A0 : ((s == 1) ? Ag1 : Ag2);
                const unsigned short* ar = ag + (size_t)m * D;
#pragma unroll
                for (int kt = 0; kt < 8; ++kt) {
                    const bf16x8 a = *(const bf16x8*)&ar[kt * 16 + l5 * 8];
#pragma unroll
                    for (int nt = 0; nt < 4; ++nt) {
                        const bf16x8 b = *(const bf16x8*)&WL[((kt * 4 + nt) * 64 + lane) * 8];
                        acc[nt] = __builtin_amdgcn_mfma_f32_32x32x16_bf16(b, a, acc[nt], 0, 0, 0);
                    }
                }
            }
        }
    }

    if (active) {
        float* orow = out + (size_t)m * D;
#pragma unroll
        for (int nt = 0; nt < 4; ++nt) {
            float* p = orow + nt * 32 + 4 * l5;
            *(float4*)(p + 0)  = make_float4(acc[nt][0],  acc[nt][1],  acc[nt][2],  acc[nt][3]);
            *(float4*)(p + 8)  = make_float4(acc[nt][4],  acc[nt][5],  acc[nt][6],  acc[nt][7]);
            *(float4*)(p + 16) = make_float4(acc[nt][8],  acc[nt][9],  acc[nt][10], acc[nt][11]);
            *(float4*)(p + 24) = make_float4(acc[nt][12], acc[nt][13], acc[nt][14], acc[nt][15]);
        }
    }
}

extern "C" void kernel_launch(void* const* d_in, const int* in_sizes, int n_in,
                              void* d_out, int out_size, void* d_ws, size_t ws_size,
                              hipStream_t stream)
{
    const float* x_gene  = (const float*)d_in[0];
    const float* x_trait = (const float*)d_in[1];
    const int* src_gg = (const int*)d_in[2];
    const int* dst_gg = (const int*)d_in[3];
    const int* src_gt = (const int*)d_in[4];
    const int* dst_gt = (const int*)d_in[5];
    const int* src_tg = (const int*)d_in[6];
    const int* dst_tg = (const int*)d_in[7];
    const float* Wn_gg = (const float*)d_in[8];
    const float* Ws_gg = (const float*)d_in[9];
    const float* b_gg  = (const float*)d_in[10];
    const float* Wn_gt = (const float*)d_in[11];
    const float* Ws_gt = (const float*)d_in[12];
    const float* b_gt  = (const float*)d_in[13];
    const float* Wn_tg = (const float*)d_in[14];
    const float* Ws_tg = (const float*)d_in[15];
    const float* b_tg  = (const float*)d_in[16];

    const int nE_gg = in_sizes[2];
    const int nE_gt = in_sizes[4];
    const int nE_tg = in_sizes[6];

    float* out_gene  = (float*)d_out;
    float* out_trait = (float*)d_out + (size_t)NG * D;

    // ws: xb_gene bf16 [NG*D] | aggA bf16 [NG*D] | aggB bf16 [NG*D] |
    //     WpG | WpT | biasG | biasT | off [NSEG+1] | cur [NSEG] | part | sorted
    unsigned short* xb_gene = (unsigned short*)d_ws;
    unsigned short* aggA = xb_gene + (size_t)NG * D;
    unsigned short* aggB = aggA + (size_t)NG * D;
    char* p = (char*)(aggB + (size_t)NG * D);
    unsigned short* WpG = (unsigned short*)p;  p += 24 * 4 * 64 * 8 * sizeof(unsigned short);
    unsigned short* WpT = (unsigned short*)p;  p += 16 * 4 * 64 * 8 * sizeof(unsigned short);
    float* biasG = (float*)p;                  p += D * sizeof(float);
    float* biasT = (float*)p;                  p += D * sizeof(float);
    int* off    = (int*)p;                     p += (size_t)(NSEG + 1) * sizeof(int);
    int* cur    = (int*)p;                     p += (size_t)NSEG * sizeof(int);
    int* part   = (int*)p;                     p += 256 * sizeof(int);
    int* sorted = (int*)p;

    const int tb = 256;

    // weight pack + bias fold; bf16 gene feature table
    prep_kernel<<<41, 256, 0, stream>>>(Ws_gg, Ws_tg, Wn_gg, Wn_tg, Ws_gt, Wn_gt,
                                        b_gg, b_tg, b_gt, WpG, WpT, biasG, biasT);
    cvt_kernel<<<(NG * D / 8 + 255) / 256, 256, 0, stream>>>(x_gene, xb_gene, NG * D / 8);

    // CSR build (concatenated over etypes)
    hipMemsetAsync(cur, 0, (size_t)NSEG * sizeof(int), stream);
    deg_kernel<<<(nE_gg + tb - 1) / tb, tb, 0, stream>>>(dst_gg, cur, nE_gg);
    deg_kernel<<<(nE_gt + tb - 1) / tb, tb, 0, stream>>>(dst_gt, cur + NG, nE_gt);
    deg_kernel<<<(nE_tg + tb - 1) / tb, tb, 0, stream>>>(dst_tg, cur + NG + NT, nE_tg);

    scan_partial_kernel<<<SCAN_NB, SCAN_TPB, 0, stream>>>(cur, part, NSEG);
    scan_parts_kernel<<<1, SCAN_TPB, 0, stream>>>(part, SCAN_NB);
    scan_apply_kernel<<<SCAN_NB, SCAN_TPB, 0, stream>>>(cur, part, off, NSEG);

    hipMemcpyAsync(cur, off, (size_t)NSEG * sizeof(int), hipMemcpyDeviceToDevice, stream);
    fill_kernel<<<(nE_gg + tb - 1) / tb, tb, 0, stream>>>(src_gg, dst_gg, cur, sorted, nE_gg);
    fill_kernel<<<(nE_gt + tb - 1) / tb, tb, 0, stream>>>(src_gt, dst_gt, cur + NG, sorted, nE_gt);
    fill_kernel<<<(nE_tg + tb - 1) / tb, tb, 0, stream>>>(src_tg, dst_tg, cur + NG + NT, sorted, nE_tg);

    // aggregate (bf16 out), then one overwrite GEMM per node set
    const int gemm_blocks = ((NG + 31) / 32 + 15) / 16;   // 196 for 100k rows

    agg_kernel<true ><<<(NG + 3) / 4, 256, 0, stream>>>(xb_gene, off,           sorted, aggA, NG); // gg
    agg_kernel<false><<<(NG + 3) / 4, 256, 0, stream>>>(x_trait, off + NG + NT, sorted, aggB, NG); // tg
    gemm_kernel<3, false><<<gemm_blocks, 1024, 0, stream>>>(xb_gene, aggA, aggB, WpG, biasG, out_gene, NG);

    agg_kernel<true ><<<(NT + 3) / 4, 256, 0, stream>>>(xb_gene, off + NG,      sorted, aggA, NT); // gt
    gemm_kernel<2, true ><<<gemm_blocks, 1024, 0, stream>>>(x_trait, aggA, nullptr, WpT, biasT, out_trait, NT);
}

// Round 6
// 355.514 us; speedup vs baseline: 3.3978x; 1.0399x over previous
//
#include <hip/hip_runtime.h>
#include <hip/hip_bf16.h>

// HeteroGCN: 3x SAGEConv(mean).
// R1: CSR + gather aggregation (no output atomics).
// R2: hierarchical scan over concatenated degree counters.
// R3: bf16 MFMA GEMM with K-concatenation, packed weights, single pass per output.
// R4: bf16 gene feature table; unrolled gather.
// R5: 16-lane-group-per-node gather (32 row-loads in flight per wave, no tail),
//     bf16 trait table when ws_size allows, fused deg/fill launches.

#define D 128
#define NG 100000
#define NT 100000
#define NSEG (NG + NT + NG)   // concatenated dst-node counters: gg | gt | tg

typedef __bf16 bf16x8 __attribute__((ext_vector_type(8)));
typedef float f32x16 __attribute__((ext_vector_type(16)));

static __device__ __forceinline__ unsigned short f2bf(float f) {
    return __builtin_bit_cast(unsigned short, (__bf16)f);
}
static __device__ __forceinline__ float bflo(unsigned int v) {
    return __builtin_bit_cast(float, v << 16);
}
static __device__ __forceinline__ float bfhi(unsigned int v) {
    return __builtin_bit_cast(float, v & 0xffff0000u);
}

// ---------------- fp32 -> bf16 feature table ----------------
__global__ __launch_bounds__(256) void cvt_kernel(
    const float* __restrict__ x, unsigned short* __restrict__ xb, int n8)
{
    const int i = blockIdx.x * 256 + threadIdx.x;
    if (i >= n8) return;
    const float4 f0 = ((const float4*)x)[i * 2];
    const float4 f1 = ((const float4*)x)[i * 2 + 1];
    uint4 o;
    o.x = (unsigned int)f2bf(f0.x) | ((unsigned int)f2bf(f0.y) << 16);
    o.y = (unsigned int)f2bf(f0.z) | ((unsigned int)f2bf(f0.w) << 16);
    o.z = (unsigned int)f2bf(f1.x) | ((unsigned int)f2bf(f1.y) << 16);
    o.w = (unsigned int)f2bf(f1.z) | ((unsigned int)f2bf(f1.w) << 16);
    ((uint4*)xb)[i] = o;
}

// ---------------- weight pack + bias fold ----------------
// B-frag slot (kt, nt, lane, j) holds W[kt*16 + (lane>>5)*8 + j][nt*32 + (lane&31)]
__global__ __launch_bounds__(256) void prep_kernel(
    const float* __restrict__ Ws_gg, const float* __restrict__ Ws_tg,
    const float* __restrict__ Wn_gg, const float* __restrict__ Wn_tg,
    const float* __restrict__ Ws_gt, const float* __restrict__ Wn_gt,
    const float* __restrict__ b_gg, const float* __restrict__ b_tg,
    const float* __restrict__ b_gt,
    unsigned short* __restrict__ WpG, unsigned short* __restrict__ WpT,
    float* __restrict__ biasG, float* __restrict__ biasT)
{
    const int gid = blockIdx.x * 256 + threadIdx.x;
    if (gid < 6144) {                       // gene pack: 24 kt * 4 nt * 64 lanes
        const int lane = gid & 63, nt = (gid >> 6) & 3, kt = gid >> 8;
        const int n = nt * 32 + (lane & 31);
        const int kb = kt * 16 + (lane >> 5) * 8;
        unsigned int pk[4];
#pragma unroll
        for (int jj = 0; jj < 4; ++jj) {
            unsigned int w2 = 0;
#pragma unroll
            for (int h = 0; h < 2; ++h) {
                const int k = kb + jj * 2 + h;
                float w;
                if (k < 128)      w = Ws_gg[k * D + n] + Ws_tg[k * D + n];
                else if (k < 256) w = Wn_gg[(k - 128) * D + n];
                else              w = Wn_tg[(k - 256) * D + n];
                w2 |= ((unsigned int)f2bf(w)) << (16 * h);
            }
            pk[jj] = w2;
        }
        *(uint4*)(WpG + (size_t)gid * 8) = make_uint4(pk[0], pk[1], pk[2], pk[3]);
    } else if (gid < 6144 + 4096) {         // trait pack: 16 kt * 4 nt * 64 lanes
        const int g = gid - 6144;
        const int lane = g & 63, nt = (g >> 6) & 3, kt = g >> 8;
        const int n = nt * 32 + (lane & 31);
        const int kb = kt * 16 + (lane >> 5) * 8;
        unsigned int pk[4];
#pragma unroll
        for (int jj = 0; jj < 4; ++jj) {
            unsigned int w2 = 0;
#pragma unroll
            for (int h = 0; h < 2; ++h) {
                const int k = kb + jj * 2 + h;
                const float w = (k < 128) ? Ws_gt[k * D + n] : Wn_gt[(k - 128) * D + n];
                w2 |= ((unsigned int)f2bf(w)) << (16 * h);
            }
            pk[jj] = w2;
        }
        *(uint4*)(WpT + (size_t)g * 8) = make_uint4(pk[0], pk[1], pk[2], pk[3]);
    } else if (gid < 6144 + 4096 + 128) {
        const int i = gid - (6144 + 4096);
        biasG[i] = b_gg[i] + b_tg[i];
    } else if (gid < 6144 + 4096 + 256) {
        const int i = gid - (6144 + 4096 + 128);
        biasT[i] = b_gt[i];
    }
}

// ---------------- CSR build ----------------
__global__ __launch_bounds__(256) void deg3_kernel(
    const int* __restrict__ d0, int n0, const int* __restrict__ d1, int n1,
    const int* __restrict__ d2, int n2, int* __restrict__ deg)
{
    const int i = blockIdx.x * 256 + threadIdx.x;
    if (i < n0)                atomicAdd(&deg[d0[i]], 1);
    else if (i < n0 + n1)      atomicAdd(&deg[NG + d1[i - n0]], 1);
    else if (i < n0 + n1 + n2) atomicAdd(&deg[NG + NT + d2[i - n0 - n1]], 1);
}

__global__ __launch_bounds__(256) void fill3_kernel(
    const int* __restrict__ s0, const int* __restrict__ d0, int n0,
    const int* __restrict__ s1, const int* __restrict__ d1, int n1,
    const int* __restrict__ s2, const int* __restrict__ d2, int n2,
    int* __restrict__ cur, int* __restrict__ sorted)
{
    const int i = blockIdx.x * 256 + threadIdx.x;
    int srcv, seg;
    if (i < n0)                { srcv = s0[i];           seg = d0[i]; }
    else if (i < n0 + n1)      { srcv = s1[i - n0];      seg = NG + d1[i - n0]; }
    else if (i < n0 + n1 + n2) { srcv = s2[i - n0 - n1]; seg = NG + NT + d2[i - n0 - n1]; }
    else return;
    const int p = atomicAdd(&cur[seg], 1);
    sorted[p] = srcv;
}

constexpr int SCAN_TPB = 256;
constexpr int SCAN_EPT = 8;
constexpr int SCAN_EPB = SCAN_TPB * SCAN_EPT;               // 2048
constexpr int SCAN_NB  = (NSEG + SCAN_EPB - 1) / SCAN_EPB;  // 147

__global__ __launch_bounds__(SCAN_TPB) void scan_partial_kernel(
    const int* __restrict__ deg, int* __restrict__ part, int n)
{
    __shared__ int lds[SCAN_TPB];
    const int t = threadIdx.x;
    const int base = blockIdx.x * SCAN_EPB + t * SCAN_EPT;
    int s = 0;
#pragma unroll
    for (int j = 0; j < SCAN_EPT; ++j) {
        int i = base + j;
        if (i < n) s += deg[i];
    }
    lds[t] = s;
    __syncthreads();
    for (int sh = SCAN_TPB / 2; sh > 0; sh >>= 1) {
        if (t < sh) lds[t] += lds[t + sh];
        __syncthreads();
    }
    if (t == 0) part[blockIdx.x] = lds[0];
}

__global__ __launch_bounds__(SCAN_TPB) void scan_parts_kernel(
    int* __restrict__ part, int nblocks)
{
    __shared__ int lds[SCAN_TPB];
    const int t = threadIdx.x;
    const int v = (t < nblocks) ? part[t] : 0;
    lds[t] = v;
    __syncthreads();
    for (int sh = 1; sh < SCAN_TPB; sh <<= 1) {
        int u = (t >= sh) ? lds[t - sh] : 0;
        __syncthreads();
        lds[t] += u;
        __syncthreads();
    }
    if (t < nblocks) part[t] = lds[t] - v;
}

__global__ __launch_bounds__(SCAN_TPB) void scan_apply_kernel(
    const int* __restrict__ deg, const int* __restrict__ part,
    int* __restrict__ off, int n)
{
    __shared__ int lds[SCAN_TPB];
    const int t = threadIdx.x;
    const int base = blockIdx.x * SCAN_EPB + t * SCAN_EPT;
    int loc[SCAN_EPT];
    int s = 0;
#pragma unroll
    for (int j = 0; j < SCAN_EPT; ++j) {
        int i = base + j;
        loc[j] = (i < n) ? deg[i] : 0;
        s += loc[j];
    }
    lds[t] = s;
    __syncthreads();
    for (int sh = 1; sh < SCAN_TPB; sh <<= 1) {
        int u = (t >= sh) ? lds[t - sh] : 0;
        __syncthreads();
        lds[t] += u;
        __syncthreads();
    }
    int run = part[blockIdx.x] + lds[t] - s;
#pragma unroll
    for (int j = 0; j < SCAN_EPT; ++j) {
        int i = base + j;
        if (i < n) {
            off[i] = run;
            run += loc[j];
            if (i == n - 1) off[n] = run;
        }
    }
}

// ---------------- aggregation: 16-lane group per node ----------------
// 256 threads = 16 nodes/block. Lane l of a group covers cols l*8..l*8+7.
// Per loop iteration each group issues 2 independent edge-row loads -> a wave
// keeps 32 row-fetches in flight. Per-group exec-masked loop, no tail code.
template<bool BF16SRC>
__global__ __launch_bounds__(256) void agg_kernel(
    const void* __restrict__ xsrc, const int* __restrict__ off,
    const int* __restrict__ sorted, unsigned short* __restrict__ agg, int n_dst)
{
    const int t = threadIdx.x;
    const int node = blockIdx.x * 16 + (t >> 4);
    if (node >= n_dst) return;
    const int l = t & 15;
    const int s0 = off[node];
    const int s1 = off[node + 1];
    float a0 = 0.f, a1 = 0.f, a2 = 0.f, a3 = 0.f, a4 = 0.f, a5 = 0.f, a6 = 0.f, a7 = 0.f;
    int e = s0;
    if constexpr (BF16SRC) {
        const unsigned short* xb = (const unsigned short*)xsrc;
        for (; e + 1 < s1; e += 2) {
            const int i0 = sorted[e], i1 = sorted[e + 1];
            const uint4 v0 = *(const uint4*)(xb + (size_t)i0 * D + l * 8);
            const uint4 v1 = *(const uint4*)(xb + (size_t)i1 * D + l * 8);
            a0 += bflo(v0.x) + bflo(v1.x);  a1 += bfhi(v0.x) + bfhi(v1.x);
            a2 += bflo(v0.y) + bflo(v1.y);  a3 += bfhi(v0.y) + bfhi(v1.y);
            a4 += bflo(v0.z) + bflo(v1.z);  a5 += bfhi(v0.z) + bfhi(v1.z);
            a6 += bflo(v0.w) + bflo(v1.w);  a7 += bfhi(v0.w) + bfhi(v1.w);
        }
        if (e < s1) {
            const uint4 v0 = *(const uint4*)(xb + (size_t)sorted[e] * D + l * 8);
            a0 += bflo(v0.x);  a1 += bfhi(v0.x);
            a2 += bflo(v0.y);  a3 += bfhi(v0.y);
            a4 += bflo(v0.z);  a5 += bfhi(v0.z);
            a6 += bflo(v0.w);  a7 += bfhi(v0.w);
        }
    } else {
        const float* x = (const float*)xsrc;
        for (; e + 1 < s1; e += 2) {
            const int i0 = sorted[e], i1 = sorted[e + 1];
            const float4 u0 = *(const float4*)(x + (size_t)i0 * D + l * 8);
            const float4 u1 = *(const float4*)(x + (size_t)i0 * D + l * 8 + 4);
            const float4 w0 = *(const float4*)(x + (size_t)i1 * D + l * 8);
            const float4 w1 = *(const float4*)(x + (size_t)i1 * D + l * 8 + 4);
            a0 += u0.x + w0.x; a1 += u0.y + w0.y; a2 += u0.z + w0.z; a3 += u0.w + w0.w;
            a4 += u1.x + w1.x; a5 += u1.y + w1.y; a6 += u1.z + w1.z; a7 += u1.w + w1.w;
        }
        if (e < s1) {
            const int i0 = sorted[e];
            const float4 u0 = *(const float4*)(x + (size_t)i0 * D + l * 8);
            const float4 u1 = *(const float4*)(x + (size_t)i0 * D + l * 8 + 4);
            a0 += u0.x; a1 += u0.y; a2 += u0.z; a3 += u0.w;
            a4 += u1.x; a5 += u1.y; a6 += u1.z; a7 += u1.w;
        }
    }
    const float inv = 1.0f / (float)max(s1 - s0, 1);
    uint4 o;
    o.x = (unsigned int)f2bf(a0 * inv) | ((unsigned int)f2bf(a1 * inv) << 16);
    o.y = (unsigned int)f2bf(a2 * inv) | ((unsigned int)f2bf(a3 * inv) << 16);
    o.z = (unsigned int)f2bf(a4 * inv) | ((unsigned int)f2bf(a5 * inv) << 16);
    o.w = (unsigned int)f2bf(a6 * inv) | ((unsigned int)f2bf(a7 * inv) << 16);
    *(uint4*)(agg + (size_t)node * D + l * 8) = o;
}

// ---------------- MFMA GEMM: out[m][n] = concat_A[m][:] @ Wcat + bias ----------------
template<int NSRC, bool SELF_F32>
__global__ __launch_bounds__(1024) void gemm_kernel(
    const void* __restrict__ A0,
    const unsigned short* __restrict__ Ag1,
    const unsigned short* __restrict__ Ag2,
    const unsigned short* __restrict__ Wpack,
    const float* __restrict__ bias,
    float* __restrict__ out, int M)
{
    __shared__ unsigned short WL[8 * 4 * 64 * 8];   // 32 KiB: one source slice
    const int t = threadIdx.x;
    const int wid = t >> 6, lane = t & 63;
    const int lm = lane & 31, l5 = lane >> 5;
    const int tiles = (M + 31) >> 5;
    const int tile = blockIdx.x * 16 + wid;
    const bool active = tile < tiles;
    const int m = tile * 32 + lm;

    f32x16 acc[4];
    if (active) {
#pragma unroll
        for (int nt = 0; nt < 4; ++nt) {
#pragma unroll
            for (int q = 0; q < 4; ++q) {
                const float4 bq = *(const float4*)&bias[nt * 32 + 4 * l5 + 8 * q];
                acc[nt][4 * q + 0] = bq.x; acc[nt][4 * q + 1] = bq.y;
                acc[nt][4 * q + 2] = bq.z; acc[nt][4 * q + 3] = bq.w;
            }
        }
    }

    const uint4* wg = (const uint4*)Wpack;
    uint4* wl = (uint4*)WL;

    for (int s = 0; s < NSRC; ++s) {
        __syncthreads();
        wl[t]        = wg[(size_t)s * 2048 + t];
        wl[t + 1024] = wg[(size_t)s * 2048 + t + 1024];
        __syncthreads();
        if (active) {
            if (s == 0 && SELF_F32) {
                const float* ar = (const float*)A0 + (size_t)m * D;
#pragma unroll
                for (int kt = 0; kt < 8; ++kt) {
                    const float4 f0 = *(const float4*)&ar[kt * 16 + l5 * 8];
                    const float4 f1 = *(const float4*)&ar[kt * 16 + l5 * 8 + 4];
                    bf16x8 a;
                    a[0] = (__bf16)f0.x; a[1] = (__bf16)f0.y; a[2] = (__bf16)f0.z; a[3] = (__bf16)f0.w;
                    a[4] = (__bf16)f1.x; a[5] = (__bf16)f1.y; a[6] = (__bf16)f1.z; a[7] = (__bf16)f1.w;
#pragma unroll
                    for (int nt = 0; nt < 4; ++nt) {
                        const bf16x8 b = *(const bf16x8*)&WL[((kt * 4 + nt) * 64 + lane) * 8];
                        acc[nt] = __builtin_amdgcn_mfma_f32_32x32x16_bf16(b, a, acc[nt], 0, 0, 0);
                    }
                }
            } else {
                const unsigned short* ag =
                    (s == 0) ? (const unsigned short*)A0 : ((s == 1) ? Ag1 : Ag2);
                const unsigned short* ar = ag + (size_t)m * D;
#pragma unroll
                for (int kt = 0; kt < 8; ++kt) {
                    const bf16x8 a = *(const bf16x8*)&ar[kt * 16 + l5 * 8];
#pragma unroll
                    for (int nt = 0; nt < 4; ++nt) {
                        const bf16x8 b = *(const bf16x8*)&WL[((kt * 4 + nt) * 64 + lane) * 8];
                        acc[nt] = __builtin_amdgcn_mfma_f32_32x32x16_bf16(b, a, acc[nt], 0, 0, 0);
                    }
                }
            }
        }
    }

    if (active) {
        float* orow = out + (size_t)m * D;
#pragma unroll
        for (int nt = 0; nt < 4; ++nt) {
            float* p = orow + nt * 32 + 4 * l5;
            *(float4*)(p + 0)  = make_float4(acc[nt][0],  acc[nt][1],  acc[nt][2],  acc[nt][3]);
            *(float4*)(p + 8)  = make_float4(acc[nt][4],  acc[nt][5],  acc[nt][6],  acc[nt][7]);
            *(float4*)(p + 16) = make_float4(acc[nt][8],  acc[nt][9],  acc[nt][10], acc[nt][11]);
            *(float4*)(p + 24) = make_float4(acc[nt][12], acc[nt][13], acc[nt][14], acc[nt][15]);
        }
    }
}

extern "C" void kernel_launch(void* const* d_in, const int* in_sizes, int n_in,
                              void* d_out, int out_size, void* d_ws, size_t ws_size,
                              hipStream_t stream)
{
    const float* x_gene  = (const float*)d_in[0];
    const float* x_trait = (const float*)d_in[1];
    const int* src_gg = (const int*)d_in[2];
    const int* dst_gg = (const int*)d_in[3];
    const int* src_gt = (const int*)d_in[4];
    const int* dst_gt = (const int*)d_in[5];
    const int* src_tg = (const int*)d_in[6];
    const int* dst_tg = (const int*)d_in[7];
    const float* Wn_gg = (const float*)d_in[8];
    const float* Ws_gg = (const float*)d_in[9];
    const float* b_gg  = (const float*)d_in[10];
    const float* Wn_gt = (const float*)d_in[11];
    const float* Ws_gt = (const float*)d_in[12];
    const float* b_gt  = (const float*)d_in[13];
    const float* Wn_tg = (const float*)d_in[14];
    const float* Ws_tg = (const float*)d_in[15];
    const float* b_tg  = (const float*)d_in[16];

    const int nE_gg = in_sizes[2];
    const int nE_gt = in_sizes[4];
    const int nE_tg = in_sizes[6];
    const int nE_total = nE_gg + nE_gt + nE_tg;

    float* out_gene  = (float*)d_out;
    float* out_trait = (float*)d_out + (size_t)NG * D;

    // ws: xb_gene | aggA | aggB | WpG | WpT | biasG | biasT | off | cur | part |
    //     sorted | [xb_trait if ws_size allows]
    unsigned short* xb_gene = (unsigned short*)d_ws;
    unsigned short* aggA = xb_gene + (size_t)NG * D;
    unsigned short* aggB = aggA + (size_t)NG * D;
    char* p = (char*)(aggB + (size_t)NG * D);
    unsigned short* WpG = (unsigned short*)p;  p += 24 * 4 * 64 * 8 * sizeof(unsigned short);
    unsigned short* WpT = (unsigned short*)p;  p += 16 * 4 * 64 * 8 * sizeof(unsigned short);
    float* biasG = (float*)p;                  p += D * sizeof(float);
    float* biasT = (float*)p;                  p += D * sizeof(float);
    int* off    = (int*)p;                     p += (size_t)(NSEG + 1) * sizeof(int);
    int* cur    = (int*)p;                     p += (size_t)NSEG * sizeof(int);
    int* part   = (int*)p;                     p += 256 * sizeof(int);
    int* sorted = (int*)p;                     p += (size_t)nE_total * sizeof(int);
    unsigned short* xb_trait = (unsigned short*)p;
    const bool use_bft =
        ((char*)(xb_trait + (size_t)NT * D) - (char*)d_ws) <= (ptrdiff_t)ws_size;

    const int tb = 256;

    // weight pack + bias fold; bf16 feature tables
    prep_kernel<<<41, 256, 0, stream>>>(Ws_gg, Ws_tg, Wn_gg, Wn_tg, Ws_gt, Wn_gt,
                                        b_gg, b_tg, b_gt, WpG, WpT, biasG, biasT);
    cvt_kernel<<<(NG * D / 8 + 255) / 256, 256, 0, stream>>>(x_gene, xb_gene, NG * D / 8);
    if (use_bft)
        cvt_kernel<<<(NT * D / 8 + 255) / 256, 256, 0, stream>>>(x_trait, xb_trait, NT * D / 8);

    // CSR build (concatenated over etypes)
    hipMemsetAsync(cur, 0, (size_t)NSEG * sizeof(int), stream);
    deg3_kernel<<<(nE_total + tb - 1) / tb, tb, 0, stream>>>(
        dst_gg, nE_gg, dst_gt, nE_gt, dst_tg, nE_tg, cur);

    scan_partial_kernel<<<SCAN_NB, SCAN_TPB, 0, stream>>>(cur, part, NSEG);
    scan_parts_kernel<<<1, SCAN_TPB, 0, stream>>>(part, SCAN_NB);
    scan_apply_kernel<<<SCAN_NB, SCAN_TPB, 0, stream>>>(cur, part, off, NSEG);

    hipMemcpyAsync(cur, off, (size_t)NSEG * sizeof(int), hipMemcpyDeviceToDevice, stream);
    fill3_kernel<<<(nE_total + tb - 1) / tb, tb, 0, stream>>>(
        src_gg, dst_gg, nE_gg, src_gt, dst_gt, nE_gt, src_tg, dst_tg, nE_tg, cur, sorted);

    // aggregate (bf16 out), then one overwrite GEMM per node set
    const int gemm_blocks = ((NG + 31) / 32 + 15) / 16;   // 196 for 100k rows
    const int agg_g = (NG + 15) / 16;
    const int agg_t = (NT + 15) / 16;

    agg_kernel<true><<<agg_g, 256, 0, stream>>>(xb_gene, off, sorted, aggA, NG);          // gg
    if (use_bft)
        agg_kernel<true ><<<agg_g, 256, 0, stream>>>(xb_trait, off + NG + NT, sorted, aggB, NG); // tg
    else
        agg_kernel<false><<<agg_g, 256, 0, stream>>>(x_trait,  off + NG + NT, sorted, aggB, NG); // tg
    gemm_kernel<3, false><<<gemm_blocks, 1024, 0, stream>>>(xb_gene, aggA, aggB, WpG, biasG, out_gene, NG);

    agg_kernel<true><<<agg_t, 256, 0, stream>>>(xb_gene, off + NG, sorted, aggA, NT);     // gt
    if (use_bft)
        gemm_kernel<2, false><<<gemm_blocks, 1024, 0, stream>>>(xb_trait, aggA, nullptr, WpT, biasT, out_trait, NT);
    else
        gemm_kernel<2, true ><<<gemm_blocks, 1024, 0, stream>>>(x_trait,  aggA, nullptr, WpT, biasT, out_trait, NT);
}

// Round 7
// 234.534 us; speedup vs baseline: 5.1505x; 1.5158x over previous
//
#include <hip/hip_runtime.h>
#include <hip/hip_bf16.h>

// HeteroGCN: 3x SAGEConv(mean).
// R1: CSR + gather aggregation (no output atomics).
// R2: hierarchical scan over concatenated degree counters.
// R3: bf16 MFMA GEMM with K-concatenation, packed weights, single pass per output.
// R4: bf16 gene feature table; unrolled gather.
// R5: 16-lane-group-per-node gather; bf16 trait table when ws allows.
// R6: CSR build rewritten as two-phase LDS binning (multi-split): random 4B
//     scatter (90MB HBM write-through) -> bucket-contiguous coalesced dumps +
//     per-bucket LDS scatter. deg/scan/fill/memcpy kernels all replaced.

#define D 128
#define NG 100000
#define NT 100000
#define NSEG (NG + NT + NG)   // concatenated dst-node counters: gg | gt | tg

#define NBUCK 256
#define NPB   ((NSEG + NBUCK - 1) / NBUCK)   // 1172 seg-nodes per bucket
#define TILE  4096                            // edges per bscatter workgroup

typedef __bf16 bf16x8 __attribute__((ext_vector_type(8)));
typedef float f32x16 __attribute__((ext_vector_type(16)));

static __device__ __forceinline__ unsigned short f2bf(float f) {
    return __builtin_bit_cast(unsigned short, (__bf16)f);
}
static __device__ __forceinline__ float bflo(unsigned int v) {
    return __builtin_bit_cast(float, v << 16);
}
static __device__ __forceinline__ float bfhi(unsigned int v) {
    return __builtin_bit_cast(float, v & 0xffff0000u);
}

// ---------------- fp32 -> bf16 feature table ----------------
__global__ __launch_bounds__(256) void cvt_kernel(
    const float* __restrict__ x, unsigned short* __restrict__ xb, int n8)
{
    const int i = blockIdx.x * 256 + threadIdx.x;
    if (i >= n8) return;
    const float4 f0 = ((const float4*)x)[i * 2];
    const float4 f1 = ((const float4*)x)[i * 2 + 1];
    uint4 o;
    o.x = (unsigned int)f2bf(f0.x) | ((unsigned int)f2bf(f0.y) << 16);
    o.y = (unsigned int)f2bf(f0.z) | ((unsigned int)f2bf(f0.w) << 16);
    o.z = (unsigned int)f2bf(f1.x) | ((unsigned int)f2bf(f1.y) << 16);
    o.w = (unsigned int)f2bf(f1.z) | ((unsigned int)f2bf(f1.w) << 16);
    ((uint4*)xb)[i] = o;
}

// ---------------- weight pack + bias fold ----------------
// B-frag slot (kt, nt, lane, j) holds W[kt*16 + (lane>>5)*8 + j][nt*32 + (lane&31)]
__global__ __launch_bounds__(256) void prep_kernel(
    const float* __restrict__ Ws_gg, const float* __restrict__ Ws_tg,
    const float* __restrict__ Wn_gg, const float* __restrict__ Wn_tg,
    const float* __restrict__ Ws_gt, const float* __restrict__ Wn_gt,
    const float* __restrict__ b_gg, const float* __restrict__ b_tg,
    const float* __restrict__ b_gt,
    unsigned short* __restrict__ WpG, unsigned short* __restrict__ WpT,
    float* __restrict__ biasG, float* __restrict__ biasT)
{
    const int gid = blockIdx.x * 256 + threadIdx.x;
    if (gid < 6144) {                       // gene pack: 24 kt * 4 nt * 64 lanes
        const int lane = gid & 63, nt = (gid >> 6) & 3, kt = gid >> 8;
        const int n = nt * 32 + (lane & 31);
        const int kb = kt * 16 + (lane >> 5) * 8;
        unsigned int pk[4];
#pragma unroll
        for (int jj = 0; jj < 4; ++jj) {
            unsigned int w2 = 0;
#pragma unroll
            for (int h = 0; h < 2; ++h) {
                const int k = kb + jj * 2 + h;
                float w;
                if (k < 128)      w = Ws_gg[k * D + n] + Ws_tg[k * D + n];
                else if (k < 256) w = Wn_gg[(k - 128) * D + n];
                else              w = Wn_tg[(k - 256) * D + n];
                w2 |= ((unsigned int)f2bf(w)) << (16 * h);
            }
            pk[jj] = w2;
        }
        *(uint4*)(WpG + (size_t)gid * 8) = make_uint4(pk[0], pk[1], pk[2], pk[3]);
    } else if (gid < 6144 + 4096) {         // trait pack: 16 kt * 4 nt * 64 lanes
        const int g = gid - 6144;
        const int lane = g & 63, nt = (g >> 6) & 3, kt = g >> 8;
        const int n = nt * 32 + (lane & 31);
        const int kb = kt * 16 + (lane >> 5) * 8;
        unsigned int pk[4];
#pragma unroll
        for (int jj = 0; jj < 4; ++jj) {
            unsigned int w2 = 0;
#pragma unroll
            for (int h = 0; h < 2; ++h) {
                const int k = kb + jj * 2 + h;
                const float w = (k < 128) ? Ws_gt[k * D + n] : Wn_gt[(k - 128) * D + n];
                w2 |= ((unsigned int)f2bf(w)) << (16 * h);
            }
            pk[jj] = w2;
        }
        *(uint4*)(WpT + (size_t)g * 8) = make_uint4(pk[0], pk[1], pk[2], pk[3]);
    } else if (gid < 6144 + 4096 + 128) {
        const int i = gid - (6144 + 4096);
        biasG[i] = b_gg[i] + b_tg[i];
    } else if (gid < 6144 + 4096 + 256) {
        const int i = gid - (6144 + 4096 + 128);
        biasT[i] = b_gt[i];
    }
}

// ---------------- binning phase A ----------------
// seg id for fused edge index (gg | gt | tg concatenation)
static __device__ __forceinline__ int edge_seg(
    int ge, const int* d0, int n0, const int* d1, int n1, const int* d2)
{
    if (ge < n0) return d0[ge];
    if (ge < n0 + n1) return NG + d1[ge - n0];
    return NG + NT + d2[ge - n0 - n1];
}
static __device__ __forceinline__ int edge_src(
    int ge, const int* s0, int n0, const int* s1, int n1, const int* s2)
{
    if (ge < n0) return s0[ge];
    if (ge < n0 + n1) return s1[ge - n0];
    return s2[ge - n0 - n1];
}

// A1: per-bucket histogram (LDS hist per WG -> 256 global adds)
__global__ __launch_bounds__(256) void bcount_kernel(
    const int* __restrict__ d0, int n0, const int* __restrict__ d1, int n1,
    const int* __restrict__ d2, int nE, int* __restrict__ bcount)
{
    __shared__ int hist[NBUCK];
    const int t = threadIdx.x;
    hist[t] = 0;
    __syncthreads();
    const int base = blockIdx.x * TILE;
#pragma unroll
    for (int j = 0; j < TILE / 256; ++j) {
        const int ge = base + j * 256 + t;
        if (ge < nE) {
            const int seg = edge_seg(ge, d0, n0, d1, n1, d2);
            atomicAdd(&hist[seg / NPB], 1);
        }
    }
    __syncthreads();
    if (hist[t]) atomicAdd(&bcount[t], hist[t]);
}

// A2: exclusive scan of 256 bucket counts -> base[257], cursor init, off[NSEG]
__global__ __launch_bounds__(256) void bscan_kernel(
    const int* __restrict__ bcount, int* __restrict__ bbase,
    int* __restrict__ bcursor, int* __restrict__ off)
{
    __shared__ int lds[NBUCK];
    const int t = threadIdx.x;
    const int v = bcount[t];
    lds[t] = v;
    __syncthreads();
    for (int sh = 1; sh < NBUCK; sh <<= 1) {
        int u = (t >= sh) ? lds[t - sh] : 0;
        __syncthreads();
        lds[t] += u;
        __syncthreads();
    }
    const int excl = lds[t] - v;
    bbase[t] = excl;
    bcursor[t] = excl;
    if (t == NBUCK - 1) {
        bbase[NBUCK] = lds[t];
        off[NSEG] = lds[t];
    }
}

// A3: LDS multi-split scatter: stage a tile, reorder by bucket, reserve global
// space with ONE atomic per bucket per WG, dump bucket-contiguous (src,seg).
__global__ __launch_bounds__(256) void bscatter_kernel(
    const int* __restrict__ s0, const int* __restrict__ d0, int n0,
    const int* __restrict__ s1, const int* __restrict__ d1, int n1,
    const int* __restrict__ s2, const int* __restrict__ d2, int nE,
    int* __restrict__ bcursor, int2* __restrict__ binned)
{
    __shared__ int2 stage[TILE];
    __shared__ int hist[NBUCK], scn[NBUCK], gbase[NBUCK], lcur[NBUCK];
    const int t = threadIdx.x;
    hist[t] = 0;
    __syncthreads();

    const int base = blockIdx.x * TILE;
    int mseg[TILE / 256], msrc[TILE / 256];
#pragma unroll
    for (int j = 0; j < TILE / 256; ++j) {
        const int ge = base + j * 256 + t;
        if (ge < nE) {
            mseg[j] = edge_seg(ge, d0, n0, d1, n1, d2);
            msrc[j] = edge_src(ge, s0, n0, s1, n1, s2);
            atomicAdd(&hist[mseg[j] / NPB], 1);
        } else mseg[j] = -1;
    }
    __syncthreads();

    // exclusive scan of hist
    const int h = hist[t];
    scn[t] = h;
    __syncthreads();
    for (int sh = 1; sh < NBUCK; sh <<= 1) {
        int u = (t >= sh) ? scn[t - sh] : 0;
        __syncthreads();
        scn[t] += u;
        __syncthreads();
    }
    const int excl = scn[t] - h;
    __syncthreads();
    scn[t] = excl;
    lcur[t] = excl;
    if (h) gbase[t] = atomicAdd(&bcursor[t], h);
    __syncthreads();

#pragma unroll
    for (int j = 0; j < TILE / 256; ++j) {
        if (mseg[j] >= 0) {
            const int b = mseg[j] / NPB;
            const int pos = atomicAdd(&lcur[b], 1);
            stage[pos] = make_int2(msrc[j], mseg[j]);
        }
    }
    __syncthreads();

    const int cnt = min(TILE, nE - base);
    for (int slot = t; slot < cnt; slot += 256) {
        const int2 pr = stage[slot];
        const int b = pr.y / NPB;
        binned[gbase[b] + (slot - scn[b])] = pr;
    }
}

// B: one WG per bucket. Per-node degree + scan + scatter entirely in LDS;
// emits off[] (coalesced) and sorted[] (bucket-local region).
__global__ __launch_bounds__(256) void bbuild_kernel(
    const int2* __restrict__ binned, const int* __restrict__ bbase,
    int* __restrict__ off, int* __restrict__ sorted)
{
    constexpr int CH = (NPB + 255) / 256;   // 5
    __shared__ int ldeg[NPB];
    __shared__ int loff[NPB];
    __shared__ int psum[256];
    const int t = threadIdx.x;
    const int b = blockIdx.x;
    const int n0 = b * NPB;
    const int NL = min(NSEG - n0, NPB);
    const int ebase = bbase[b];
    const int ecnt = bbase[b + 1] - ebase;

    for (int i = t; i < NL; i += 256) ldeg[i] = 0;
    __syncthreads();
    for (int e = t; e < ecnt; e += 256)
        atomicAdd(&ldeg[binned[ebase + e].y - n0], 1);
    __syncthreads();

    // block-wide exclusive scan over NL node degrees
    int s = 0;
#pragma unroll
    for (int k = 0; k < CH; ++k) {
        const int i = t * CH + k;
        if (i < NL) s += ldeg[i];
    }
    psum[t] = s;
    __syncthreads();
    for (int sh = 1; sh < 256; sh <<= 1) {
        int u = (t >= sh) ? psum[t - sh] : 0;
        __syncthreads();
        psum[t] += u;
        __syncthreads();
    }
    int run = psum[t] - s;
#pragma unroll
    for (int k = 0; k < CH; ++k) {
        const int i = t * CH + k;
        if (i < NL) { loff[i] = run; run += ldeg[i]; }
    }
    __syncthreads();

    for (int i = t; i < NL; i += 256) off[n0 + i] = ebase + loff[i];
    __syncthreads();

    for (int e = t; e < ecnt; e += 256) {
        const int2 pr = binned[ebase + e];
        const int slot = atomicAdd(&loff[pr.y - n0], 1);
        sorted[ebase + slot] = pr.x;
    }
}

// ---------------- aggregation: 16-lane group per node ----------------
template<bool BF16SRC>
__global__ __launch_bounds__(256) void agg_kernel(
    const void* __restrict__ xsrc, const int* __restrict__ off,
    const int* __restrict__ sorted, unsigned short* __restrict__ agg, int n_dst)
{
    const int t = threadIdx.x;
    const int node = blockIdx.x * 16 + (t >> 4);
    if (node >= n_dst) return;
    const int l = t & 15;
    const int s0 = off[node];
    const int s1 = off[node + 1];
    float a0 = 0.f, a1 = 0.f, a2 = 0.f, a3 = 0.f, a4 = 0.f, a5 = 0.f, a6 = 0.f, a7 = 0.f;
    int e = s0;
    if constexpr (BF16SRC) {
        const unsigned short* xb = (const unsigned short*)xsrc;
        for (; e + 1 < s1; e += 2) {
            const int i0 = sorted[e], i1 = sorted[e + 1];
            const uint4 v0 = *(const uint4*)(xb + (size_t)i0 * D + l * 8);
            const uint4 v1 = *(const uint4*)(xb + (size_t)i1 * D + l * 8);
            a0 += bflo(v0.x) + bflo(v1.x);  a1 += bfhi(v0.x) + bfhi(v1.x);
            a2 += bflo(v0.y) + bflo(v1.y);  a3 += bfhi(v0.y) + bfhi(v1.y);
            a4 += bflo(v0.z) + bflo(v1.z);  a5 += bfhi(v0.z) + bfhi(v1.z);
            a6 += bflo(v0.w) + bflo(v1.w);  a7 += bfhi(v0.w) + bfhi(v1.w);
        }
        if (e < s1) {
            const uint4 v0 = *(const uint4*)(xb + (size_t)sorted[e] * D + l * 8);
            a0 += bflo(v0.x);  a1 += bfhi(v0.x);
            a2 += bflo(v0.y);  a3 += bfhi(v0.y);
            a4 += bflo(v0.z);  a5 += bfhi(v0.z);
            a6 += bflo(v0.w);  a7 += bfhi(v0.w);
        }
    } else {
        const float* x = (const float*)xsrc;
        for (; e + 1 < s1; e += 2) {
            const int i0 = sorted[e], i1 = sorted[e + 1];
            const float4 u0 = *(const float4*)(x + (size_t)i0 * D + l * 8);
            const float4 u1 = *(const float4*)(x + (size_t)i0 * D + l * 8 + 4);
            const float4 w0 = *(const float4*)(x + (size_t)i1 * D + l * 8);
            const float4 w1 = *(const float4*)(x + (size_t)i1 * D + l * 8 + 4);
            a0 += u0.x + w0.x; a1 += u0.y + w0.y; a2 += u0.z + w0.z; a3 += u0.w + w0.w;
            a4 += u1.x + w1.x; a5 += u1.y + w1.y; a6 += u1.z + w1.z; a7 += u1.w + w1.w;
        }
        if (e < s1) {
            const int i0 = sorted[e];
            const float4 u0 = *(const float4*)(x + (size_t)i0 * D + l * 8);
            const float4 u1 = *(const float4*)(x + (size_t)i0 * D + l * 8 + 4);
            a0 += u0.x; a1 += u0.y; a2 += u0.z; a3 += u0.w;
            a4 += u1.x; a5 += u1.y; a6 += u1.z; a7 += u1.w;
        }
    }
    const float inv = 1.0f / (float)max(s1 - s0, 1);
    uint4 o;
    o.x = (unsigned int)f2bf(a0 * inv) | ((unsigned int)f2bf(a1 * inv) << 16);
    o.y = (unsigned int)f2bf(a2 * inv) | ((unsigned int)f2bf(a3 * inv) << 16);
    o.z = (unsigned int)f2bf(a4 * inv) | ((unsigned int)f2bf(a5 * inv) << 16);
    o.w = (unsigned int)f2bf(a6 * inv) | ((unsigned int)f2bf(a7 * inv) << 16);
    *(uint4*)(agg + (size_t)node * D + l * 8) = o;
}

// ---------------- MFMA GEMM: out[m][n] = concat_A[m][:] @ Wcat + bias ----------------
template<int NSRC, bool SELF_F32>
__global__ __launch_bounds__(1024) void gemm_kernel(
    const void* __restrict__ A0,
    const unsigned short* __restrict__ Ag1,
    const unsigned short* __restrict__ Ag2,
    const unsigned short* __restrict__ Wpack,
    const float* __restrict__ bias,
    float* __restrict__ out, int M)
{
    __shared__ unsigned short WL[8 * 4 * 64 * 8];   // 32 KiB: one source slice
    const int t = threadIdx.x;
    const int wid = t >> 6, lane = t & 63;
    const int lm = lane & 31, l5 = lane >> 5;
    const int tiles = (M + 31) >> 5;
    const int tile = blockIdx.x * 16 + wid;
    const bool active = tile < tiles;
    const int m = tile * 32 + lm;

    f32x16 acc[4];
    if (active) {
#pragma unroll
        for (int nt = 0; nt < 4; ++nt) {
#pragma unroll
            for (int q = 0; q < 4; ++q) {
                const float4 bq = *(const float4*)&bias[nt * 32 + 4 * l5 + 8 * q];
                acc[nt][4 * q + 0] = bq.x; acc[nt][4 * q + 1] = bq.y;
                acc[nt][4 * q + 2] = bq.z; acc[nt][4 * q + 3] = bq.w;
            }
        }
    }

    const uint4* wg = (const uint4*)Wpack;
    uint4* wl = (uint4*)WL;

    for (int s = 0; s < NSRC; ++s) {
        __syncthreads();
        wl[t]        = wg[(size_t)s * 2048 + t];
        wl[t + 1024] = wg[(size_t)s * 2048 + t + 1024];
        __syncthreads();
        if (active) {
            if (s == 0 && SELF_F32) {
                const float* ar = (const float*)A0 + (size_t)m * D;
#pragma unroll
                for (int kt = 0; kt < 8; ++kt) {
                    const float4 f0 = *(const float4*)&ar[kt * 16 + l5 * 8];
                    const float4 f1 = *(const float4*)&ar[kt * 16 + l5 * 8 + 4];
                    bf16x8 a;
                    a[0] = (__bf16)f0.x; a[1] = (__bf16)f0.y; a[2] = (__bf16)f0.z; a[3] = (__bf16)f0.w;
                    a[4] = (__bf16)f1.x; a[5] = (__bf16)f1.y; a[6] = (__bf16)f1.z; a[7] = (__bf16)f1.w;
#pragma unroll
                    for (int nt = 0; nt < 4; ++nt) {
                        const bf16x8 b = *(const bf16x8*)&WL[((kt * 4 + nt) * 64 + lane) * 8];
                        acc[nt] = __builtin_amdgcn_mfma_f32_32x32x16_bf16(b, a, acc[nt], 0, 0, 0);
                    }
                }
            } else {
                const unsigned short* ag =
                    (s == 0) ? (const unsigned short*)A0 : ((s == 1) ? Ag1 : Ag2);
                const unsigned short* ar = ag + (size_t)m * D;
#pragma unroll
                for (int kt = 0; kt < 8; ++kt) {
                    const bf16x8 a = *(const bf16x8*)&ar[kt * 16 + l5 * 8];
#pragma unroll
                    for (int nt = 0; nt < 4; ++nt) {
                        const bf16x8 b = *(const bf16x8*)&WL[((kt * 4 + nt) * 64 + lane) * 8];
                        acc[nt] = __builtin_amdgcn_mfma_f32_32x32x16_bf16(b, a, acc[nt], 0, 0, 0);
                    }
                }
            }
        }
    }

    if (active) {
        float* orow = out + (size_t)m * D;
#pragma unroll
        for (int nt = 0; nt < 4; ++nt) {
            float* p = orow + nt * 32 + 4 * l5;
            *(float4*)(p + 0)  = make_float4(acc[nt][0],  acc[nt][1],  acc[nt][2],  acc[nt][3]);
            *(float4*)(p + 8)  = make_float4(acc[nt][4],  acc[nt][5],  acc[nt][6],  acc[nt][7]);
            *(float4*)(p + 16) = make_float4(acc[nt][8],  acc[nt][9],  acc[nt][10], acc[nt][11]);
            *(float4*)(p + 24) = make_float4(acc[nt][12], acc[nt][13], acc[nt][14], acc[nt][15]);
        }
    }
}

extern "C" void kernel_launch(void* const* d_in, const int* in_sizes, int n_in,
                              void* d_out, int out_size, void* d_ws, size_t ws_size,
                              hipStream_t stream)
{
    const float* x_gene  = (const float*)d_in[0];
    const float* x_trait = (const float*)d_in[1];
    const int* src_gg = (const int*)d_in[2];
    const int* dst_gg = (const int*)d_in[3];
    const int* src_gt = (const int*)d_in[4];
    const int* dst_gt = (const int*)d_in[5];
    const int* src_tg = (const int*)d_in[6];
    const int* dst_tg = (const int*)d_in[7];
    const float* Wn_gg = (const float*)d_in[8];
    const float* Ws_gg = (const float*)d_in[9];
    const float* b_gg  = (const float*)d_in[10];
    const float* Wn_gt = (const float*)d_in[11];
    const float* Ws_gt = (const float*)d_in[12];
    const float* b_gt  = (const float*)d_in[13];
    const float* Wn_tg = (const float*)d_in[14];
    const float* Ws_tg = (const float*)d_in[15];
    const float* b_tg  = (const float*)d_in[16];

    const int nE_gg = in_sizes[2];
    const int nE_gt = in_sizes[4];
    const int nE_tg = in_sizes[6];
    const int nE_total = nE_gg + nE_gt + nE_tg;

    float* out_gene  = (float*)d_out;
    float* out_trait = (float*)d_out + (size_t)NG * D;

    // ws: xb_gene | aggA | aggB | WpG | WpT | biasG | biasT | off | bcount |
    //     bbase | bcursor | sorted | [xb_trait if ws allows]
    // binned (12 MB) aliases aggA (dead until after bbuild).
    unsigned short* xb_gene = (unsigned short*)d_ws;
    unsigned short* aggA = xb_gene + (size_t)NG * D;
    unsigned short* aggB = aggA + (size_t)NG * D;
    int2* binned = (int2*)aggA;
    char* p = (char*)(aggB + (size_t)NG * D);
    unsigned short* WpG = (unsigned short*)p;  p += 24 * 4 * 64 * 8 * sizeof(unsigned short);
    unsigned short* WpT = (unsigned short*)p;  p += 16 * 4 * 64 * 8 * sizeof(unsigned short);
    float* biasG = (float*)p;                  p += D * sizeof(float);
    float* biasT = (float*)p;                  p += D * sizeof(float);
    int* off     = (int*)p;                    p += (size_t)(NSEG + 1) * sizeof(int);
    int* bcount  = (int*)p;                    p += NBUCK * sizeof(int);
    int* bbase   = (int*)p;                    p += (NBUCK + 1) * sizeof(int);
    int* bcursor = (int*)p;                    p += NBUCK * sizeof(int);
    int* sorted  = (int*)p;                    p += (size_t)nE_total * sizeof(int);
    unsigned short* xb_trait = (unsigned short*)p;
    const bool use_bft =
        ((char*)(xb_trait + (size_t)NT * D) - (char*)d_ws) <= (ptrdiff_t)ws_size;

    // weight pack + bias fold; bf16 feature tables
    prep_kernel<<<41, 256, 0, stream>>>(Ws_gg, Ws_tg, Wn_gg, Wn_tg, Ws_gt, Wn_gt,
                                        b_gg, b_tg, b_gt, WpG, WpT, biasG, biasT);
    cvt_kernel<<<(NG * D / 8 + 255) / 256, 256, 0, stream>>>(x_gene, xb_gene, NG * D / 8);
    if (use_bft)
        cvt_kernel<<<(NT * D / 8 + 255) / 256, 256, 0, stream>>>(x_trait, xb_trait, NT * D / 8);

    // CSR build via two-phase binning
    const int nWG = (nE_total + TILE - 1) / TILE;
    hipMemsetAsync(bcount, 0, NBUCK * sizeof(int), stream);
    bcount_kernel<<<nWG, 256, 0, stream>>>(dst_gg, nE_gg, dst_gt, nE_gt, dst_tg,
                                           nE_total, bcount);
    bscan_kernel<<<1, 256, 0, stream>>>(bcount, bbase, bcursor, off);
    bscatter_kernel<<<nWG, 256, 0, stream>>>(
        src_gg, dst_gg, nE_gg, src_gt, dst_gt, nE_gt, src_tg, dst_tg,
        nE_total, bcursor, binned);
    bbuild_kernel<<<NBUCK, 256, 0, stream>>>(binned, bbase, off, sorted);

    // aggregate (bf16 out), then one overwrite GEMM per node set
    const int gemm_blocks = ((NG + 31) / 32 + 15) / 16;   // 196 for 100k rows
    const int agg_g = (NG + 15) / 16;
    const int agg_t = (NT + 15) / 16;

    agg_kernel<true><<<agg_g, 256, 0, stream>>>(xb_gene, off, sorted, aggA, NG);          // gg
    if (use_bft)
        agg_kernel<true ><<<agg_g, 256, 0, stream>>>(xb_trait, off + NG + NT, sorted, aggB, NG); // tg
    else
        agg_kernel<false><<<agg_g, 256, 0, stream>>>(x_trait,  off + NG + NT, sorted, aggB, NG); // tg
    gemm_kernel<3, false><<<gemm_blocks, 1024, 0, stream>>>(xb_gene, aggA, aggB, WpG, biasG, out_gene, NG);

    agg_kernel<true><<<agg_t, 256, 0, stream>>>(xb_gene, off + NG, sorted, aggA, NT);     // gt
    if (use_bft)
        gemm_kernel<2, false><<<gemm_blocks, 1024, 0, stream>>>(xb_trait, aggA, nullptr, WpT, biasT, out_trait, NT);
    else
        gemm_kernel<2, true ><<<gemm_blocks, 1024, 0, stream>>>(x_trait,  aggA, nullptr, WpT, biasT, out_trait, NT);
}

// Round 8
// 218.335 us; speedup vs baseline: 5.5326x; 1.0742x over previous
//
#include <hip/hip_runtime.h>
#include <hip/hip_bf16.h>

// HeteroGCN: 3x SAGEConv(mean).
// R1: CSR + gather aggregation (no output atomics).
// R2: hierarchical scan over concatenated degree counters.
// R3: bf16 MFMA GEMM with K-concatenation, packed weights, single pass per output.
// R4: bf16 gene feature table; unrolled gather.
// R5: 16-lane-group-per-node gather; bf16 trait table when ws allows.
// R6: CSR build via two-phase LDS binning (coalesced, few atomics).
// R7: single fused agg over all 300k dst nodes, 4-deep clamped-index gather
//     (4 row-loads in flight per group, ~2.7 latency waits per node), aggC
//     buffer removes the gt-after-gemm false dependency.

#define D 128
#define NG 100000
#define NT 100000
#define NSEG (NG + NT + NG)   // concatenated dst-node counters: gg | gt | tg

#define NBUCK 256
#define NPB   ((NSEG + NBUCK - 1) / NBUCK)   // 1172 seg-nodes per bucket
#define TILE  4096                            // edges per bscatter workgroup

typedef __bf16 bf16x8 __attribute__((ext_vector_type(8)));
typedef float f32x16 __attribute__((ext_vector_type(16)));

static __device__ __forceinline__ unsigned short f2bf(float f) {
    return __builtin_bit_cast(unsigned short, (__bf16)f);
}
static __device__ __forceinline__ float bflo(unsigned int v) {
    return __builtin_bit_cast(float, v << 16);
}
static __device__ __forceinline__ float bfhi(unsigned int v) {
    return __builtin_bit_cast(float, v & 0xffff0000u);
}

// ---------------- fp32 -> bf16 feature table ----------------
__global__ __launch_bounds__(256) void cvt_kernel(
    const float* __restrict__ x, unsigned short* __restrict__ xb, int n8)
{
    const int i = blockIdx.x * 256 + threadIdx.x;
    if (i >= n8) return;
    const float4 f0 = ((const float4*)x)[i * 2];
    const float4 f1 = ((const float4*)x)[i * 2 + 1];
    uint4 o;
    o.x = (unsigned int)f2bf(f0.x) | ((unsigned int)f2bf(f0.y) << 16);
    o.y = (unsigned int)f2bf(f0.z) | ((unsigned int)f2bf(f0.w) << 16);
    o.z = (unsigned int)f2bf(f1.x) | ((unsigned int)f2bf(f1.y) << 16);
    o.w = (unsigned int)f2bf(f1.z) | ((unsigned int)f2bf(f1.w) << 16);
    ((uint4*)xb)[i] = o;
}

// ---------------- weight pack + bias fold ----------------
// B-frag slot (kt, nt, lane, j) holds W[kt*16 + (lane>>5)*8 + j][nt*32 + (lane&31)]
__global__ __launch_bounds__(256) void prep_kernel(
    const float* __restrict__ Ws_gg, const float* __restrict__ Ws_tg,
    const float* __restrict__ Wn_gg, const float* __restrict__ Wn_tg,
    const float* __restrict__ Ws_gt, const float* __restrict__ Wn_gt,
    const float* __restrict__ b_gg, const float* __restrict__ b_tg,
    const float* __restrict__ b_gt,
    unsigned short* __restrict__ WpG, unsigned short* __restrict__ WpT,
    float* __restrict__ biasG, float* __restrict__ biasT)
{
    const int gid = blockIdx.x * 256 + threadIdx.x;
    if (gid < 6144) {                       // gene pack: 24 kt * 4 nt * 64 lanes
        const int lane = gid & 63, nt = (gid >> 6) & 3, kt = gid >> 8;
        const int n = nt * 32 + (lane & 31);
        const int kb = kt * 16 + (lane >> 5) * 8;
        unsigned int pk[4];
#pragma unroll
        for (int jj = 0; jj < 4; ++jj) {
            unsigned int w2 = 0;
#pragma unroll
            for (int h = 0; h < 2; ++h) {
                const int k = kb + jj * 2 + h;
                float w;
                if (k < 128)      w = Ws_gg[k * D + n] + Ws_tg[k * D + n];
                else if (k < 256) w = Wn_gg[(k - 128) * D + n];
                else              w = Wn_tg[(k - 256) * D + n];
                w2 |= ((unsigned int)f2bf(w)) << (16 * h);
            }
            pk[jj] = w2;
        }
        *(uint4*)(WpG + (size_t)gid * 8) = make_uint4(pk[0], pk[1], pk[2], pk[3]);
    } else if (gid < 6144 + 4096) {         // trait pack: 16 kt * 4 nt * 64 lanes
        const int g = gid - 6144;
        const int lane = g & 63, nt = (g >> 6) & 3, kt = g >> 8;
        const int n = nt * 32 + (lane & 31);
        const int kb = kt * 16 + (lane >> 5) * 8;
        unsigned int pk[4];
#pragma unroll
        for (int jj = 0; jj < 4; ++jj) {
            unsigned int w2 = 0;
#pragma unroll
            for (int h = 0; h < 2; ++h) {
                const int k = kb + jj * 2 + h;
                const float w = (k < 128) ? Ws_gt[k * D + n] : Wn_gt[(k - 128) * D + n];
                w2 |= ((unsigned int)f2bf(w)) << (16 * h);
            }
            pk[jj] = w2;
        }
        *(uint4*)(WpT + (size_t)g * 8) = make_uint4(pk[0], pk[1], pk[2], pk[3]);
    } else if (gid < 6144 + 4096 + 128) {
        const int i = gid - (6144 + 4096);
        biasG[i] = b_gg[i] + b_tg[i];
    } else if (gid < 6144 + 4096 + 256) {
        const int i = gid - (6144 + 4096 + 128);
        biasT[i] = b_gt[i];
    }
}

// ---------------- binning phase A ----------------
static __device__ __forceinline__ int edge_seg(
    int ge, const int* d0, int n0, const int* d1, int n1, const int* d2)
{
    if (ge < n0) return d0[ge];
    if (ge < n0 + n1) return NG + d1[ge - n0];
    return NG + NT + d2[ge - n0 - n1];
}
static __device__ __forceinline__ int edge_src(
    int ge, const int* s0, int n0, const int* s1, int n1, const int* s2)
{
    if (ge < n0) return s0[ge];
    if (ge < n0 + n1) return s1[ge - n0];
    return s2[ge - n0 - n1];
}

// A1: per-bucket histogram (LDS hist per WG -> 256 global adds)
__global__ __launch_bounds__(256) void bcount_kernel(
    const int* __restrict__ d0, int n0, const int* __restrict__ d1, int n1,
    const int* __restrict__ d2, int nE, int* __restrict__ bcount)
{
    __shared__ int hist[NBUCK];
    const int t = threadIdx.x;
    hist[t] = 0;
    __syncthreads();
    const int base = blockIdx.x * TILE;
#pragma unroll
    for (int j = 0; j < TILE / 256; ++j) {
        const int ge = base + j * 256 + t;
        if (ge < nE) {
            const int seg = edge_seg(ge, d0, n0, d1, n1, d2);
            atomicAdd(&hist[seg / NPB], 1);
        }
    }
    __syncthreads();
    if (hist[t]) atomicAdd(&bcount[t], hist[t]);
}

// A2: exclusive scan of 256 bucket counts -> base[257], cursor init, off[NSEG]
__global__ __launch_bounds__(256) void bscan_kernel(
    const int* __restrict__ bcount, int* __restrict__ bbase,
    int* __restrict__ bcursor, int* __restrict__ off)
{
    __shared__ int lds[NBUCK];
    const int t = threadIdx.x;
    const int v = bcount[t];
    lds[t] = v;
    __syncthreads();
    for (int sh = 1; sh < NBUCK; sh <<= 1) {
        int u = (t >= sh) ? lds[t - sh] : 0;
        __syncthreads();
        lds[t] += u;
        __syncthreads();
    }
    const int excl = lds[t] - v;
    bbase[t] = excl;
    bcursor[t] = excl;
    if (t == NBUCK - 1) {
        bbase[NBUCK] = lds[t];
        off[NSEG] = lds[t];
    }
}

// A3: LDS multi-split scatter: stage tile, reorder by bucket, reserve global
// space with ONE atomic per bucket per WG, dump bucket-contiguous (src,seg).
__global__ __launch_bounds__(256) void bscatter_kernel(
    const int* __restrict__ s0, const int* __restrict__ d0, int n0,
    const int* __restrict__ s1, const int* __restrict__ d1, int n1,
    const int* __restrict__ s2, const int* __restrict__ d2, int nE,
    int* __restrict__ bcursor, int2* __restrict__ binned)
{
    __shared__ int2 stage[TILE];
    __shared__ int hist[NBUCK], scn[NBUCK], gbase[NBUCK], lcur[NBUCK];
    const int t = threadIdx.x;
    hist[t] = 0;
    __syncthreads();

    const int base = blockIdx.x * TILE;
    int mseg[TILE / 256], msrc[TILE / 256];
#pragma unroll
    for (int j = 0; j < TILE / 256; ++j) {
        const int ge = base + j * 256 + t;
        if (ge < nE) {
            mseg[j] = edge_seg(ge, d0, n0, d1, n1, d2);
            msrc[j] = edge_src(ge, s0, n0, s1, n1, s2);
            atomicAdd(&hist[mseg[j] / NPB], 1);
        } else mseg[j] = -1;
    }
    __syncthreads();

    const int h = hist[t];
    scn[t] = h;
    __syncthreads();
    for (int sh = 1; sh < NBUCK; sh <<= 1) {
        int u = (t >= sh) ? scn[t - sh] : 0;
        __syncthreads();
        scn[t] += u;
        __syncthreads();
    }
    const int excl = scn[t] - h;
    __syncthreads();
    scn[t] = excl;
    lcur[t] = excl;
    if (h) gbase[t] = atomicAdd(&bcursor[t], h);
    __syncthreads();

#pragma unroll
    for (int j = 0; j < TILE / 256; ++j) {
        if (mseg[j] >= 0) {
            const int b = mseg[j] / NPB;
            const int pos = atomicAdd(&lcur[b], 1);
            stage[pos] = make_int2(msrc[j], mseg[j]);
        }
    }
    __syncthreads();

    const int cnt = min(TILE, nE - base);
    for (int slot = t; slot < cnt; slot += 256) {
        const int2 pr = stage[slot];
        const int b = pr.y / NPB;
        binned[gbase[b] + (slot - scn[b])] = pr;
    }
}

// B: one WG per bucket. Per-node degree + scan + scatter entirely in LDS.
__global__ __launch_bounds__(256) void bbuild_kernel(
    const int2* __restrict__ binned, const int* __restrict__ bbase,
    int* __restrict__ off, int* __restrict__ sorted)
{
    constexpr int CH = (NPB + 255) / 256;   // 5
    __shared__ int ldeg[NPB];
    __shared__ int loff[NPB];
    __shared__ int psum[256];
    const int t = threadIdx.x;
    const int b = blockIdx.x;
    const int n0 = b * NPB;
    const int NL = min(NSEG - n0, NPB);
    const int ebase = bbase[b];
    const int ecnt = bbase[b + 1] - ebase;

    for (int i = t; i < NL; i += 256) ldeg[i] = 0;
    __syncthreads();
    for (int e = t; e < ecnt; e += 256)
        atomicAdd(&ldeg[binned[ebase + e].y - n0], 1);
    __syncthreads();

    int s = 0;
#pragma unroll
    for (int k = 0; k < CH; ++k) {
        const int i = t * CH + k;
        if (i < NL) s += ldeg[i];
    }
    psum[t] = s;
    __syncthreads();
    for (int sh = 1; sh < 256; sh <<= 1) {
        int u = (t >= sh) ? psum[t - sh] : 0;
        __syncthreads();
        psum[t] += u;
        __syncthreads();
    }
    int run = psum[t] - s;
#pragma unroll
    for (int k = 0; k < CH; ++k) {
        const int i = t * CH + k;
        if (i < NL) { loff[i] = run; run += ldeg[i]; }
    }
    __syncthreads();

    for (int i = t; i < NL; i += 256) off[n0 + i] = ebase + loff[i];
    __syncthreads();

    for (int e = t; e < ecnt; e += 256) {
        const int2 pr = binned[ebase + e];
        const int slot = atomicAdd(&loff[pr.y - n0], 1);
        sorted[ebase + slot] = pr.x;
    }
}

// ---------------- fused aggregation over all NSEG nodes ----------------
// 16-lane group per node, 4-deep clamped-index gather: every chunk issues 4
// independent row loads (OOB slots reload the last index -> cache hit, row
// zeroed before accumulate). Segment picks src table + output buffer.
template<bool TRAIT_BF16>
__global__ __launch_bounds__(256) void agg_all_kernel(
    const unsigned short* __restrict__ xg, const void* __restrict__ xt,
    const int* __restrict__ off, const int* __restrict__ sorted,
    unsigned short* __restrict__ aggA, unsigned short* __restrict__ aggC,
    unsigned short* __restrict__ aggB)
{
    const int t = threadIdx.x;
    const int node = blockIdx.x * 16 + (t >> 4);
    if (node >= NSEG) return;
    const int l = t & 15;
    const int s0 = off[node];
    const int s1 = off[node + 1];

    const unsigned short* xb = xg;
    unsigned short* out;
    int local;
    bool bf_path = true;
    if (node < NG)            { out = aggA; local = node; }
    else if (node < NG + NT)  { out = aggC; local = node - NG; }
    else {
        out = aggB; local = node - NG - NT;
        if constexpr (TRAIT_BF16) xb = (const unsigned short*)xt;
        else bf_path = false;
    }

    float a0 = 0.f, a1 = 0.f, a2 = 0.f, a3 = 0.f, a4 = 0.f, a5 = 0.f, a6 = 0.f, a7 = 0.f;

    if (TRAIT_BF16 || bf_path) {
        for (int e = s0; e < s1; e += 4) {
            const int i0 = sorted[e];
            const int i1 = sorted[min(e + 1, s1 - 1)];
            const int i2 = sorted[min(e + 2, s1 - 1)];
            const int i3 = sorted[min(e + 3, s1 - 1)];
            uint4 v0 = *(const uint4*)(xb + (size_t)i0 * D + l * 8);
            uint4 v1 = *(const uint4*)(xb + (size_t)i1 * D + l * 8);
            uint4 v2 = *(const uint4*)(xb + (size_t)i2 * D + l * 8);
            uint4 v3 = *(const uint4*)(xb + (size_t)i3 * D + l * 8);
            if (e + 1 >= s1) v1 = make_uint4(0, 0, 0, 0);
            if (e + 2 >= s1) v2 = make_uint4(0, 0, 0, 0);
            if (e + 3 >= s1) v3 = make_uint4(0, 0, 0, 0);
            a0 += bflo(v0.x) + bflo(v1.x) + bflo(v2.x) + bflo(v3.x);
            a1 += bfhi(v0.x) + bfhi(v1.x) + bfhi(v2.x) + bfhi(v3.x);
            a2 += bflo(v0.y) + bflo(v1.y) + bflo(v2.y) + bflo(v3.y);
            a3 += bfhi(v0.y) + bfhi(v1.y) + bfhi(v2.y) + bfhi(v3.y);
            a4 += bflo(v0.z) + bflo(v1.z) + bflo(v2.z) + bflo(v3.z);
            a5 += bfhi(v0.z) + bfhi(v1.z) + bfhi(v2.z) + bfhi(v3.z);
            a6 += bflo(v0.w) + bflo(v1.w) + bflo(v2.w) + bflo(v3.w);
            a7 += bfhi(v0.w) + bfhi(v1.w) + bfhi(v2.w) + bfhi(v3.w);
        }
    } else {
        const float* x = (const float*)xt;
        for (int e = s0; e < s1; e += 2) {
            const int i0 = sorted[e];
            const int i1 = sorted[min(e + 1, s1 - 1)];
            float4 u0 = *(const float4*)(x + (size_t)i0 * D + l * 8);
            float4 u1 = *(const float4*)(x + (size_t)i0 * D + l * 8 + 4);
            float4 w0 = *(const float4*)(x + (size_t)i1 * D + l * 8);
            float4 w1 = *(const float4*)(x + (size_t)i1 * D + l * 8 + 4);
            if (e + 1 >= s1) {
                w0 = make_float4(0.f, 0.f, 0.f, 0.f);
                w1 = make_float4(0.f, 0.f, 0.f, 0.f);
            }
            a0 += u0.x + w0.x; a1 += u0.y + w0.y; a2 += u0.z + w0.z; a3 += u0.w + w0.w;
            a4 += u1.x + w1.x; a5 += u1.y + w1.y; a6 += u1.z + w1.z; a7 += u1.w + w1.w;
        }
    }

    const float inv = 1.0f / (float)max(s1 - s0, 1);
    uint4 o;
    o.x = (unsigned int)f2bf(a0 * inv) | ((unsigned int)f2bf(a1 * inv) << 16);
    o.y = (unsigned int)f2bf(a2 * inv) | ((unsigned int)f2bf(a3 * inv) << 16);
    o.z = (unsigned int)f2bf(a4 * inv) | ((unsigned int)f2bf(a5 * inv) << 16);
    o.w = (unsigned int)f2bf(a6 * inv) | ((unsigned int)f2bf(a7 * inv) << 16);
    *(uint4*)(out + (size_t)local * D + l * 8) = o;
}

// ---------------- MFMA GEMM: out[m][n] = concat_A[m][:] @ Wcat + bias ----------------
template<int NSRC, bool SELF_F32>
__global__ __launch_bounds__(1024) void gemm_kernel(
    const void* __restrict__ A0,
    const unsigned short* __restrict__ Ag1,
    const unsigned short* __restrict__ Ag2,
    const unsigned short* __restrict__ Wpack,
    const float* __restrict__ bias,
    float* __restrict__ out, int M)
{
    __shared__ unsigned short WL[8 * 4 * 64 * 8];   // 32 KiB: one source slice
    const int t = threadIdx.x;
    const int wid = t >> 6, lane = t & 63;
    const int lm = lane & 31, l5 = lane >> 5;
    const int tiles = (M + 31) >> 5;
    const int tile = blockIdx.x * 16 + wid;
    const bool active = tile < tiles;
    const int m = tile * 32 + lm;

    f32x16 acc[4];
    if (active) {
#pragma unroll
        for (int nt = 0; nt < 4; ++nt) {
#pragma unroll
            for (int q = 0; q < 4; ++q) {
                const float4 bq = *(const float4*)&bias[nt * 32 + 4 * l5 + 8 * q];
                acc[nt][4 * q + 0] = bq.x; acc[nt][4 * q + 1] = bq.y;
                acc[nt][4 * q + 2] = bq.z; acc[nt][4 * q + 3] = bq.w;
            }
        }
    }

    const uint4* wg = (const uint4*)Wpack;
    uint4* wl = (uint4*)WL;

    for (int s = 0; s < NSRC; ++s) {
        __syncthreads();
        wl[t]        = wg[(size_t)s * 2048 + t];
        wl[t + 1024] = wg[(size_t)s * 2048 + t + 1024];
        __syncthreads();
        if (active) {
            if (s == 0 && SELF_F32) {
                const float* ar = (const float*)A0 + (size_t)m * D;
#pragma unroll
                for (int kt = 0; kt < 8; ++kt) {
                    const float4 f0 = *(const float4*)&ar[kt * 16 + l5 * 8];
                    const float4 f1 = *(const float4*)&ar[kt * 16 + l5 * 8 + 4];
                    bf16x8 a;
                    a[0] = (__bf16)f0.x; a[1] = (__bf16)f0.y; a[2] = (__bf16)f0.z; a[3] = (__bf16)f0.w;
                    a[4] = (__bf16)f1.x; a[5] = (__bf16)f1.y; a[6] = (__bf16)f1.z; a[7] = (__bf16)f1.w;
#pragma unroll
                    for (int nt = 0; nt < 4; ++nt) {
                        const bf16x8 b = *(const bf16x8*)&WL[((kt * 4 + nt) * 64 + lane) * 8];
                        acc[nt] = __builtin_amdgcn_mfma_f32_32x32x16_bf16(b, a, acc[nt], 0, 0, 0);
                    }
                }
            } else {
                const unsigned short* ag =
                    (s == 0) ? (const unsigned short*)A0 : ((s == 1) ? Ag1 : Ag2);
                const unsigned short* ar = ag + (size_t)m * D;
#pragma unroll
                for (int kt = 0; kt < 8; ++kt) {
                    const bf16x8 a = *(const bf16x8*)&ar[kt * 16 + l5 * 8];
#pragma unroll
                    for (int nt = 0; nt < 4; ++nt) {
                        const bf16x8 b = *(const bf16x8*)&WL[((kt * 4 + nt) * 64 + lane) * 8];
                        acc[nt] = __builtin_amdgcn_mfma_f32_32x32x16_bf16(b, a, acc[nt], 0, 0, 0);
                    }
                }
            }
        }
    }

    if (active) {
        float* orow = out + (size_t)m * D;
#pragma unroll
        for (int nt = 0; nt < 4; ++nt) {
            float* p = orow + nt * 32 + 4 * l5;
            *(float4*)(p + 0)  = make_float4(acc[nt][0],  acc[nt][1],  acc[nt][2],  acc[nt][3]);
            *(float4*)(p + 8)  = make_float4(acc[nt][4],  acc[nt][5],  acc[nt][6],  acc[nt][7]);
            *(float4*)(p + 16) = make_float4(acc[nt][8],  acc[nt][9],  acc[nt][10], acc[nt][11]);
            *(float4*)(p + 24) = make_float4(acc[nt][12], acc[nt][13], acc[nt][14], acc[nt][15]);
        }
    }
}

extern "C" void kernel_launch(void* const* d_in, const int* in_sizes, int n_in,
                              void* d_out, int out_size, void* d_ws, size_t ws_size,
                              hipStream_t stream)
{
    const float* x_gene  = (const float*)d_in[0];
    const float* x_trait = (const float*)d_in[1];
    const int* src_gg = (const int*)d_in[2];
    const int* dst_gg = (const int*)d_in[3];
    const int* src_gt = (const int*)d_in[4];
    const int* dst_gt = (const int*)d_in[5];
    const int* src_tg = (const int*)d_in[6];
    const int* dst_tg = (const int*)d_in[7];
    const float* Wn_gg = (const float*)d_in[8];
    const float* Ws_gg = (const float*)d_in[9];
    const float* b_gg  = (const float*)d_in[10];
    const float* Wn_gt = (const float*)d_in[11];
    const float* Ws_gt = (const float*)d_in[12];
    const float* b_gt  = (const float*)d_in[13];
    const float* Wn_tg = (const float*)d_in[14];
    const float* Ws_tg = (const float*)d_in[15];
    const float* b_tg  = (const float*)d_in[16];

    const int nE_gg = in_sizes[2];
    const int nE_gt = in_sizes[4];
    const int nE_tg = in_sizes[6];
    const int nE_total = nE_gg + nE_gt + nE_tg;

    float* out_gene  = (float*)d_out;
    float* out_trait = (float*)d_out + (size_t)NG * D;

    // ws: xb_gene | aggA | aggB | aggC | WpG | WpT | biasG | biasT | off |
    //     bcount | bbase | bcursor | sorted | [xb_trait if ws allows]
    // binned (12 MB) aliases aggA (dead until after bbuild).
    unsigned short* xb_gene = (unsigned short*)d_ws;
    unsigned short* aggA = xb_gene + (size_t)NG * D;
    unsigned short* aggB = aggA + (size_t)NG * D;
    unsigned short* aggC = aggB + (size_t)NG * D;
    int2* binned = (int2*)aggA;
    char* p = (char*)(aggC + (size_t)NT * D);
    unsigned short* WpG = (unsigned short*)p;  p += 24 * 4 * 64 * 8 * sizeof(unsigned short);
    unsigned short* WpT = (unsigned short*)p;  p += 16 * 4 * 64 * 8 * sizeof(unsigned short);
    float* biasG = (float*)p;                  p += D * sizeof(float);
    float* biasT = (float*)p;                  p += D * sizeof(float);
    int* off     = (int*)p;                    p += (size_t)(NSEG + 1) * sizeof(int);
    int* bcount  = (int*)p;                    p += NBUCK * sizeof(int);
    int* bbase   = (int*)p;                    p += (NBUCK + 1) * sizeof(int);
    int* bcursor = (int*)p;                    p += NBUCK * sizeof(int);
    int* sorted  = (int*)p;                    p += (size_t)nE_total * sizeof(int);
    unsigned short* xb_trait = (unsigned short*)p;
    const bool use_bft =
        ((char*)(xb_trait + (size_t)NT * D) - (char*)d_ws) <= (ptrdiff_t)ws_size;

    // weight pack + bias fold; bf16 feature tables
    prep_kernel<<<41, 256, 0, stream>>>(Ws_gg, Ws_tg, Wn_gg, Wn_tg, Ws_gt, Wn_gt,
                                        b_gg, b_tg, b_gt, WpG, WpT, biasG, biasT);
    cvt_kernel<<<(NG * D / 8 + 255) / 256, 256, 0, stream>>>(x_gene, xb_gene, NG * D / 8);
    if (use_bft)
        cvt_kernel<<<(NT * D / 8 + 255) / 256, 256, 0, stream>>>(x_trait, xb_trait, NT * D / 8);

    // CSR build via two-phase binning
    const int nWG = (nE_total + TILE - 1) / TILE;
    hipMemsetAsync(bcount, 0, NBUCK * sizeof(int), stream);
    bcount_kernel<<<nWG, 256, 0, stream>>>(dst_gg, nE_gg, dst_gt, nE_gt, dst_tg,
                                           nE_total, bcount);
    bscan_kernel<<<1, 256, 0, stream>>>(bcount, bbase, bcursor, off);
    bscatter_kernel<<<nWG, 256, 0, stream>>>(
        src_gg, dst_gg, nE_gg, src_gt, dst_gt, nE_gt, src_tg, dst_tg,
        nE_total, bcursor, binned);
    bbuild_kernel<<<NBUCK, 256, 0, stream>>>(binned, bbase, off, sorted);

    // one fused aggregation over all 300k dst nodes (gg->aggA, gt->aggC, tg->aggB)
    const int agg_blocks = (NSEG + 15) / 16;
    if (use_bft)
        agg_all_kernel<true ><<<agg_blocks, 256, 0, stream>>>(
            xb_gene, xb_trait, off, sorted, aggA, aggC, aggB);
    else
        agg_all_kernel<false><<<agg_blocks, 256, 0, stream>>>(
            xb_gene, x_trait, off, sorted, aggA, aggC, aggB);

    // one overwrite GEMM per node set
    const int gemm_blocks = ((NG + 31) / 32 + 15) / 16;   // 196 for 100k rows

    gemm_kernel<3, false><<<gemm_blocks, 1024, 0, stream>>>(
        xb_gene, aggA, aggB, WpG, biasG, out_gene, NG);
    if (use_bft)
        gemm_kernel<2, false><<<gemm_blocks, 1024, 0, stream>>>(
            xb_trait, aggC, nullptr, WpT, biasT, out_trait, NT);
    else
        gemm_kernel<2, true ><<<gemm_blocks, 1024, 0, stream>>>(
            x_trait, aggC, nullptr, WpT, biasT, out_trait, NT);
}